// Round 9
// baseline (598.690 us; speedup 1.0000x reference)
//
#include <hip/hip_runtime.h>
#include <hip/hip_bf16.h>
#include <math.h>

#define D_MODEL   2048
#define D_INNER   4096
#define NHEADS    64
#define HEAD_DIM  64
#define D_STATE   128
#define CHUNK     256
#define CONV_DIM  (D_INNER + 2*D_STATE)            // 4352
#define D_IN_PROJ (2*D_INNER + 2*D_STATE + NHEADS) // 8512
#define LD_ZX     8704                             // D_IN_PROJ padded to 256
#define DT_OFF    (2*D_INNER + 2*D_STATE)          // 8448
#define BATCH     2
#define SEQ       2048
#define NCHUNK    (SEQ/CHUNK)                      // 8
#define EPS_RMS   1e-5f

typedef unsigned short u16;
typedef __attribute__((ext_vector_type(8))) unsigned short u16x8;
typedef __attribute__((ext_vector_type(4))) unsigned short u16x4;
typedef __attribute__((ext_vector_type(8))) short bf16x8;   // MFMA A/B frag (8 bf16)
typedef __attribute__((ext_vector_type(4))) float f32x4;    // MFMA C/D frag

__device__ __forceinline__ float us2f(u16 u){
    union { unsigned int i; float f; } c; c.i = ((unsigned int)u) << 16; return c.f;
}
__device__ __forceinline__ u16 f2us(float f){
    union { float f; unsigned int i; } c; c.f = f;
    unsigned int r = c.i + 0x7FFFu + ((c.i >> 16) & 1u);
    return (u16)(r >> 16);
}
__device__ __forceinline__ float siluf(float x){ return x / (1.f + expf(-x)); }

__device__ __forceinline__ void gload_lds16(const void* g, void* l) {
    __builtin_amdgcn_global_load_lds((const __attribute__((address_space(1))) void*)g,
                                     (__attribute__((address_space(3))) void*)l, 16, 0, 0);
}

#define VMCNT(n) asm volatile("s_waitcnt vmcnt(" #n ")" ::: "memory")

// stage one 128x64 bf16 half-tile (row-major, stride ldk) into LDS with T2 swizzle.
// LDS dest stays LINEAR (gload_lds requirement); the SOURCE 16B-chunk index is
// permuted within each row (chunk ^= (chunk>>3)&7)  <->  read col ^= (row&7)<<3.
__device__ __forceinline__ void stage_half(const u16* __restrict__ g, size_t ldk,
                                           u16* ldsbase, int w, int lane)
{
    #pragma unroll
    for (int cc = 0; cc < 2; cc++) {
        int cb = cc * 512 + w * 64;          // wave-uniform chunk base
        int ci = cb + lane;
        int sc = ci ^ ((ci >> 3) & 7);       // swizzled source chunk (involution)
        gload_lds16(&g[(size_t)(sc >> 3) * ldk + (sc & 7) * 8], ldsbase + cb * 8);
    }
}

// ---------- elementwise f32 -> bf16 ----------
__global__ __launch_bounds__(256)
void cvt_bf16(const float* __restrict__ in, u16* __restrict__ out, int n4)
{
    int i = blockIdx.x * 256 + threadIdx.x;
    if (i >= n4) return;
    float4 v = *(const float4*)&in[(size_t)i * 4];
    u16x4 o; o[0]=f2us(v.x); o[1]=f2us(v.y); o[2]=f2us(v.z); o[3]=f2us(v.w);
    *(u16x4*)&out[(size_t)i * 4] = o;
}

// ---------- transpose + convert: in f32 [K][N] -> out bf16 [Npad][K], zero-pad n>=N ----------
__global__ __launch_bounds__(256)
void transpose_cvt(const float* __restrict__ in, u16* __restrict__ out, int K, int N)
{
    __shared__ u16 tile[64][65];
    int k0 = blockIdx.x * 64;
    int n0 = blockIdx.y * 64;
    int t = threadIdx.x;
    #pragma unroll
    for (int q = 0; q < 16; q++) {
        int lin = q * 256 + t;
        int r = lin >> 6, c = lin & 63;
        int n = n0 + c;
        float v = (n < N) ? in[(size_t)(k0 + r) * N + n] : 0.f;
        tile[r][c] = f2us(v);
    }
    __syncthreads();
    #pragma unroll
    for (int q = 0; q < 16; q++) {
        int lin = q * 256 + t;
        int r = lin >> 6, c = lin & 63;
        out[(size_t)(n0 + r) * K + k0 + c] = tile[c][r];
    }
}

// ---------- 8-phase 256x256 MFMA GEMM (T2-swizzled LDS, plain barriers) ----------
// 512 thr = 8 waves (2M x 4N); per-wave C = 128x64; BK=64, dbuf LDS 128 KiB.
// Stage ledger (round-7 proven): p1: Ah1(t+1); p3: Bh0(t+2); p4: Bh1(t+2)+Ah0(t+2).
// Each A half-tile is read at BOTH p1 (rows 0-63) and p3 (rows 64-127) -> Ah0(t+2)
// may only be staged at p4. vmcnt(6) after p4 MFMA waits on exactly tile t+1's 4 halves.
template<typename TC>
__global__ __launch_bounds__(512, 1)
void gemm_8ph(const u16* __restrict__ Ag, const u16* __restrict__ Btg,
              TC* __restrict__ Cg, int M, int N, int K, int ldc)
{
    __shared__ u16 smA[2][2][8192];   // [dbuf][half][128*64]
    __shared__ u16 smB[2][2][8192];
    const int tid = threadIdx.x;
    const int lane = tid & 63, w = tid >> 6;
    const int wm = w >> 2, wn = w & 3;
    const int lr = lane & 15, kh = lane >> 4;
    const int swz = (lr & 7) << 3;     // read-side T2 swizzle (all frag rows ≡ lr mod 8)

    // bijective XCD swizzle (m204)
    const int nbx = N >> 8;
    const int nwg = gridDim.x;
    const int orig = blockIdx.x;
    const int qq = nwg >> 3, r8 = nwg & 7;
    const int xcd = orig & 7, loc = orig >> 3;
    const int wgid = (xcd < r8 ? xcd*(qq+1) : r8*(qq+1) + (xcd-r8)*qq) + loc;
    const int m0 = (wgid / nbx) * 256;
    const int n0 = (wgid % nbx) * 256;

    const int NT = K >> 6;

    f32x4 acc[8][4];
    #pragma unroll
    for (int i = 0; i < 8; i++)
        #pragma unroll
        for (int j = 0; j < 4; j++) acc[i][j] = (f32x4){0.f,0.f,0.f,0.f};

    // ---- prologue: tile0 {Ah0,Ah1,Bh0,Bh1} + tile1 {Ah0,Bh0,Bh1}; vmcnt(6) -> tile0 ready
    stage_half(&Ag [(size_t)(m0      ) * K      ], K, &smA[0][0][0], w, lane);
    stage_half(&Ag [(size_t)(m0 + 128) * K      ], K, &smA[0][1][0], w, lane);
    stage_half(&Btg[(size_t)(n0      ) * K      ], K, &smB[0][0][0], w, lane);
    stage_half(&Btg[(size_t)(n0 + 128) * K      ], K, &smB[0][1][0], w, lane);
    stage_half(&Ag [(size_t)(m0      ) * K + 64 ], K, &smA[1][0][0], w, lane);
    stage_half(&Btg[(size_t)(n0      ) * K + 64 ], K, &smB[1][0][0], w, lane);
    stage_half(&Btg[(size_t)(n0 + 128) * K + 64 ], K, &smB[1][1][0], w, lane);
    VMCNT(6);
    __builtin_amdgcn_s_barrier();

    for (int t = 0; t < NT; ++t) {
        const int d = t & 1;
        const u16* As = &smA[d][wm][0];
        const u16* Bs = &smB[d][wn >> 1][0];
        const int rb = (wn & 1) * 64;

        bf16x8 aF[4][2], bLo[2][2], bHi[2][2];

        // ---- phase 1: read A-lo + B-lo; stage Ah1(t+1)
        #pragma unroll
        for (int i = 0; i < 4; i++)
            #pragma unroll
            for (int ks = 0; ks < 2; ks++)
                aF[i][ks] = *(const bf16x8*)&As[(i*16 + lr)*64 + ((ks*32 + kh*8) ^ swz)];
        #pragma unroll
        for (int j = 0; j < 2; j++)
            #pragma unroll
            for (int ks = 0; ks < 2; ks++)
                bLo[j][ks] = *(const bf16x8*)&Bs[(rb + j*16 + lr)*64 + ((ks*32 + kh*8) ^ swz)];
        if (t + 1 < NT)
            stage_half(&Ag[(size_t)(m0 + 128) * K + (t+1)*64], K, &smA[d^1][1][0], w, lane);
        __builtin_amdgcn_s_barrier();
        __builtin_amdgcn_s_setprio(1);
        #pragma unroll
        for (int i = 0; i < 4; i++)
            #pragma unroll
            for (int j = 0; j < 2; j++)
                #pragma unroll
                for (int ks = 0; ks < 2; ks++)
                    acc[i][j] = __builtin_amdgcn_mfma_f32_16x16x32_bf16(aF[i][ks], bLo[j][ks], acc[i][j], 0, 0, 0);
        __builtin_amdgcn_s_setprio(0);
        __builtin_amdgcn_s_barrier();

        // ---- phase 2: read B-hi (no staging; smA[d][0] still read at p3)
        #pragma unroll
        for (int j = 0; j < 2; j++)
            #pragma unroll
            for (int ks = 0; ks < 2; ks++)
                bHi[j][ks] = *(const bf16x8*)&Bs[(rb + (2+j)*16 + lr)*64 + ((ks*32 + kh*8) ^ swz)];
        __builtin_amdgcn_s_barrier();
        __builtin_amdgcn_s_setprio(1);
        #pragma unroll
        for (int i = 0; i < 4; i++)
            #pragma unroll
            for (int j = 0; j < 2; j++)
                #pragma unroll
                for (int ks = 0; ks < 2; ks++)
                    acc[i][2+j] = __builtin_amdgcn_mfma_f32_16x16x32_bf16(aF[i][ks], bHi[j][ks], acc[i][2+j], 0, 0, 0);
        __builtin_amdgcn_s_setprio(0);
        __builtin_amdgcn_s_barrier();

        // ---- phase 3: read A-hi (overwrites aF); stage Bh0(t+2)  (B-hi LDS read done at p2)
        #pragma unroll
        for (int i = 0; i < 4; i++)
            #pragma unroll
            for (int ks = 0; ks < 2; ks++)
                aF[i][ks] = *(const bf16x8*)&As[(64 + i*16 + lr)*64 + ((ks*32 + kh*8) ^ swz)];
        if (t + 2 < NT)
            stage_half(&Btg[(size_t)(n0) * K + (t+2)*64], K, &smB[d][0][0], w, lane);
        __builtin_amdgcn_s_barrier();
        __builtin_amdgcn_s_setprio(1);
        #pragma unroll
        for (int i = 0; i < 4; i++)
            #pragma unroll
            for (int j = 0; j < 2; j++)
                #pragma unroll
                for (int ks = 0; ks < 2; ks++)
                    acc[4+i][j] = __builtin_amdgcn_mfma_f32_16x16x32_bf16(aF[i][ks], bLo[j][ks], acc[4+i][j], 0, 0, 0);
        __builtin_amdgcn_s_setprio(0);
        __builtin_amdgcn_s_barrier();

        // ---- phase 4: stage Bh1(t+2)+Ah0(t+2) (A's last read was p3); MFMA; counted vmcnt after
        if (t + 2 < NT) {
            stage_half(&Btg[(size_t)(n0 + 128) * K + (t+2)*64], K, &smB[d][1][0], w, lane);
            stage_half(&Ag [(size_t)(m0      ) * K + (t+2)*64], K, &smA[d][0][0], w, lane);
        }
        __builtin_amdgcn_s_barrier();
        __builtin_amdgcn_s_setprio(1);
        #pragma unroll
        for (int i = 0; i < 4; i++)
            #pragma unroll
            for (int j = 0; j < 2; j++)
                #pragma unroll
                for (int ks = 0; ks < 2; ks++)
                    acc[4+i][2+j] = __builtin_amdgcn_mfma_f32_16x16x32_bf16(aF[i][ks], bHi[j][ks], acc[4+i][2+j], 0, 0, 0);
        __builtin_amdgcn_s_setprio(0);
        if (t < NT - 2)       { VMCNT(6); }
        else if (t == NT - 2) { VMCNT(0); }
        __builtin_amdgcn_s_barrier();
    }

    // ---- epilogue
    #pragma unroll
    for (int mf = 0; mf < 8; mf++) {
        #pragma unroll
        for (int nf = 0; nf < 4; nf++) {
            int r = m0 + wm*128 + mf*16 + kh*4;
            int cidx = n0 + wn*64 + nf*16 + lr;
            #pragma unroll
            for (int q = 0; q < 4; q++) {
                if constexpr (sizeof(TC) == 4) Cg[(size_t)(r+q)*ldc + cidx] = acc[mf][nf][q];
                else                           Cg[(size_t)(r+q)*ldc + cidx] = f2us(acc[mf][nf][q]);
            }
        }
    }
}

// ---------- 2-phase 128x128 MFMA GEMM — used for GEMM2 ----------
template<typename TC>
__global__ __launch_bounds__(256)
void gemm_mfma(const u16* __restrict__ A, const u16* __restrict__ Bt,
               TC* __restrict__ C, int M, int N, int K, int ldc)
{
    __shared__ u16 Asm[128][32];   // 8 KB
    __shared__ u16 Bsm[128][32];   // 8 KB
    const int t = threadIdx.x;
    const int lane = t & 63, w = t >> 6;
    const int wr = w >> 1, wc = w & 1;
    const int lr = lane & 15, kh = lane >> 4;

    const int nwg = gridDim.x * gridDim.y;
    const int orig = blockIdx.y * gridDim.x + blockIdx.x;
    const int qq = nwg >> 3, r8 = nwg & 7;
    const int xcd = orig & 7, loc = orig >> 3;
    const int wgid = (xcd < r8 ? xcd*(qq+1) : r8*(qq+1) + (xcd-r8)*qq) + loc;
    const int m0 = (wgid / gridDim.x) * 128;
    const int n0 = (wgid % gridDim.x) * 128;

    f32x4 acc[4][4];
    #pragma unroll
    for (int i = 0; i < 4; i++)
        #pragma unroll
        for (int j = 0; j < 4; j++) acc[i][j] = (f32x4){0.f,0.f,0.f,0.f};

    for (int k0 = 0; k0 < K; k0 += 32) {
        #pragma unroll
        for (int i = 0; i < 2; i++) {
            int cb = i * 256 + w * 64;
            int chunk = cb + lane;
            int row = chunk >> 2, kb = chunk & 3;
            gload_lds16(&A[(size_t)(m0 + row) * K + k0 + kb * 8], &Asm[0][0] + cb * 8);
            gload_lds16(&Bt[(size_t)(n0 + row) * K + k0 + kb * 8], &Bsm[0][0] + cb * 8);
        }
        __syncthreads();
        bf16x8 af[4], bf[4];
        #pragma unroll
        for (int i = 0; i < 4; i++)
            af[i] = *(const bf16x8*)&Asm[wr*64 + i*16 + lr][kh*8];
        #pragma unroll
        for (int j = 0; j < 4; j++)
            bf[j] = *(const bf16x8*)&Bsm[wc*64 + j*16 + lr][kh*8];
        #pragma unroll
        for (int i = 0; i < 4; i++)
            #pragma unroll
            for (int j = 0; j < 4; j++)
                acc[i][j] = __builtin_amdgcn_mfma_f32_16x16x32_bf16(af[i], bf[j], acc[i][j], 0, 0, 0);
        __syncthreads();
    }
    #pragma unroll
    for (int i = 0; i < 4; i++) {
        #pragma unroll
        for (int j = 0; j < 4; j++) {
            int r = m0 + wr*64 + i*16 + kh*4;
            int cidx = n0 + wc*64 + j*16 + lr;
            #pragma unroll
            for (int q = 0; q < 4; q++) {
                if constexpr (sizeof(TC) == 4) C[(size_t)(r+q)*ldc + cidx] = acc[i][j][q];
                else                           C[(size_t)(r+q)*ldc + cidx] = f2us(acc[i][j][q]);
            }
        }
    }
}

// ---------------- conv1d (K=4) + bias + SiLU, 8 channels/thread ----------------
__global__ __launch_bounds__(256)
void conv_silu(const u16* __restrict__ zx, const float* __restrict__ cw,
               const float* __restrict__ cb, u16* __restrict__ xconv,
               u16* __restrict__ Bbuf, u16* __restrict__ Cbuf)
{
    int idx = blockIdx.x * 256 + threadIdx.x;        // < M * (CONV_DIM/8)
    int cg = idx % (CONV_DIM / 8);
    int r  = idx / (CONV_DIM / 8);
    int c0 = cg * 8;
    int l  = r & (SEQ - 1);

    float y[8];
    {
        float4 b0 = *(const float4*)&cb[c0];
        float4 b1 = *(const float4*)&cb[c0 + 4];
        y[0]=b0.x; y[1]=b0.y; y[2]=b0.z; y[3]=b0.w;
        y[4]=b1.x; y[5]=b1.y; y[6]=b1.z; y[7]=b1.w;
    }
    float cwf[8][4];
    #pragma unroll
    for (int e = 0; e < 8; e++) {
        float4 v = *(const float4*)&cw[(c0 + e) * 4];
        cwf[e][0]=v.x; cwf[e][1]=v.y; cwf[e][2]=v.z; cwf[e][3]=v.w;
    }
    #pragma unroll
    for (int k = 0; k < 4; k++) {
        if (l + k - 3 >= 0) {
            u16x8 v = *(const u16x8*)&zx[(size_t)(r + k - 3) * LD_ZX + D_INNER + c0];
            #pragma unroll
            for (int e = 0; e < 8; e++) y[e] += us2f(v[e]) * cwf[e][k];
        }
    }
    u16x8 o;
    #pragma unroll
    for (int e = 0; e < 8; e++) {
        float s = y[e] / (1.f + expf(-y[e]));
        o[e] = f2us(s);
    }
    if (c0 < D_INNER)                *(u16x8*)&xconv[(size_t)r * D_INNER + c0] = o;
    else if (c0 < D_INNER + D_STATE) *(u16x8*)&Bbuf[(size_t)r * D_STATE + (c0 - D_INNER)] = o;
    else                             *(u16x8*)&Cbuf[(size_t)r * D_STATE + (c0 - D_INNER - D_STATE)] = o;
}

// ---------------- dt softplus + per-chunk cumsum ----------------
__global__ __launch_bounds__(256)
void dt_acs(const u16* __restrict__ zx, const float* __restrict__ Aparam,
            const float* __restrict__ dt_bias, float* __restrict__ dtT,
            float* __restrict__ Acs)
{
    __shared__ float sb[CHUNK];
    int blk = blockIdx.x;
    int c = blk & 7, h = (blk >> 3) & 63, b = blk >> 9;
    int t = threadIdx.x;
    int lg = c * CHUNK + t;
    int row = b * SEQ + lg;
    float x = us2f(zx[(size_t)row * LD_ZX + DT_OFF + h]) + dt_bias[h];
    float dt = (x > 20.f) ? x : log1pf(expf(x));
    float v = dt * Aparam[h];
    sb[t] = v; __syncthreads();
    #pragma unroll
    for (int off = 1; off < 256; off <<= 1) {
        float add = (t >= off) ? sb[t - off] : 0.f;
        __syncthreads();
        v += add; sb[t] = v;
        __syncthreads();
    }
    int o = (b * NHEADS + h) * SEQ + lg;
    dtT[o] = dt;
    Acs[o] = v;
}

// ---------------- per-chunk states via MFMA ----------------
__global__ __launch_bounds__(256)
void chunk_states_mfma(const u16* __restrict__ xconv, const u16* __restrict__ Bbuf,
                       const float* __restrict__ dtT, const float* __restrict__ Acs,
                       float* __restrict__ states)
{
    __shared__ u16 Btsh[128][72];
    __shared__ u16 xtsh[64][72];
    __shared__ float acs_sh[CHUNK];
    __shared__ float dt_sh[CHUNK];

    const int blk = blockIdx.x;
    const int h = blk & 63, c = (blk >> 6) & 7, b = blk >> 9;
    const int t = threadIdx.x;
    const int lane = t & 63, w = t >> 6;
    const int wr = w >> 1, wc = w & 1;
    const int lr = lane & 15, kh = lane >> 4;
    const int bh = b * NHEADS + h;
    const size_t rowbase = (size_t)(b * SEQ + c * CHUNK);

    acs_sh[t] = Acs[(size_t)bh * SEQ + c * CHUNK + t];
    dt_sh[t]  = dtT[(size_t)bh * SEQ + c * CHUNK + t];
    __syncthreads();
    const float acs_last = acs_sh[CHUNK - 1];

    f32x4 acc[2][4];
    #pragma unroll
    for (int i = 0; i < 2; i++)
        #pragma unroll
        for (int j = 0; j < 4; j++) acc[i][j] = (f32x4){0.f,0.f,0.f,0.f};

    for (int lt = 0; lt < 4; lt++) {
        __syncthreads();
        const int s = t & 63;
        const int sg = lt * 64 + s;
        const float wgt = dt_sh[sg] * expf(acs_last - acs_sh[sg]);
        {
            int ng = (t >> 6) * 32;
            const u16* src = &Bbuf[(rowbase + sg) * D_STATE + ng];
            #pragma unroll
            for (int q = 0; q < 4; q++) {
                u16x8 v = *(const u16x8*)&src[q * 8];
                #pragma unroll
                for (int e = 0; e < 8; e++)
                    Btsh[ng + q*8 + e][s] = f2us(us2f(v[e]) * wgt);
            }
        }
        {
            int pg = (t >> 6) * 16;
            const u16* src = &xconv[(rowbase + sg) * D_INNER + h * HEAD_DIM + pg];
            u16x8 v0 = *(const u16x8*)&src[0];
            u16x8 v1 = *(const u16x8*)&src[8];
            #pragma unroll
            for (int e = 0; e < 8; e++) { xtsh[pg + e][s] = v0[e]; xtsh[pg + 8 + e][s] = v1[e]; }
        }
        __syncthreads();
        #pragma unroll
        for (int kk = 0; kk < 2; kk++) {
            bf16x8 af[2], bf[4];
            #pragma unroll
            for (int i = 0; i < 2; i++)
                af[i] = *(const bf16x8*)&xtsh[wr*32 + i*16 + lr][kk*32 + kh*8];
            #pragma unroll
            for (int j = 0; j < 4; j++)
                bf[j] = *(const bf16x8*)&Btsh[wc*64 + j*16 + lr][kk*32 + kh*8];
            #pragma unroll
            for (int i = 0; i < 2; i++)
                #pragma unroll
                for (int j = 0; j < 4; j++)
                    acc[i][j] = __builtin_amdgcn_mfma_f32_16x16x32_bf16(af[i], bf[j], acc[i][j], 0, 0, 0);
        }
    }
    size_t base = ((size_t)((b*NCHUNK + c)*NHEADS + h)) * (HEAD_DIM * D_STATE);
    #pragma unroll
    for (int i = 0; i < 2; i++) {
        #pragma unroll
        for (int j = 0; j < 4; j++) {
            int p = wr*32 + i*16 + kh*4;
            int n = wc*64 + j*16 + lr;
            #pragma unroll
            for (int q = 0; q < 4; q++)
                states[base + (size_t)(p + q) * D_STATE + n] = acc[i][j][q];
        }
    }
}

// ---------------- inter-chunk recurrence ----------------
__global__ __launch_bounds__(256)
void state_recurrence(float* __restrict__ states, const float* __restrict__ Acs)
{
    int idx = blockIdx.x * 256 + threadIdx.x;
    int pn = idx & 8191;
    int bh = idx >> 13;
    int b = bh >> 6, h = bh & 63;
    float E = 0.f;
    for (int c = 0; c < NCHUNK; c++) {
        size_t off = ((size_t)((b*NCHUNK + c)*NHEADS + h)) * 8192 + pn;
        float s = states[off];
        states[off] = E;
        float cs = Acs[(size_t)(b*NHEADS + h) * SEQ + c*CHUNK + 255];
        E = expf(cs) * E + s;
    }
}

// ---------------- chunk output, MFMA ----------------
__global__ __launch_bounds__(256, 1)
void chunk_output_mfma(const u16* __restrict__ xconv, const u16* __restrict__ Bbuf,
                       const u16* __restrict__ Cbuf, const float* __restrict__ dtT,
                       const float* __restrict__ Acs, const float* __restrict__ states,
                       const float* __restrict__ Dparam, u16* __restrict__ Y)
{
    __shared__ u16 Bsm[64][130];
    __shared__ u16 xt[64][66];
    __shared__ u16 Pt[4][64][66];
    __shared__ float acs_sh[CHUNK];
    __shared__ float dt_sh[CHUNK];

    const int blk = blockIdx.x;
    const int h = blk & 63, c = (blk >> 6) & 7, b = blk >> 9;
    const int t = threadIdx.x;
    const int lane = t & 63, w = t >> 6;
    const int lr = lane & 15, kh = lane >> 4;
    const int bh = b * NHEADS + h;
    const size_t rowbase = (size_t)(b * SEQ + c * CHUNK);

    acs_sh[t] = Acs[(size_t)bh * SEQ + c * CHUNK + t];
    dt_sh[t]  = dtT[(size_t)bh * SEQ + c * CHUNK + t];

    bf16x8 af[4][4];
    #pragma unroll
    for (int i = 0; i < 4; i++)
        #pragma unroll
        for (int kk = 0; kk < 4; kk++)
            af[i][kk] = *(const bf16x8*)&Cbuf[(rowbase + w*64 + i*16 + lr) * D_STATE + kk*32 + kh*8];

    f32x4 yacc[4][4];
    #pragma unroll
    for (int i = 0; i < 4; i++)
        #pragma unroll
        for (int j = 0; j < 4; j++) yacc[i][j] = (f32x4){0.f,0.f,0.f,0.f};

    for (int st = 0; st < 4; st++) {
        __syncthreads();
        {
            int sr = t >> 2, cg = (t & 3) * 32;
            const u16* src = &Bbuf[(rowbase + st*64 + sr) * D_STATE + cg];
            #pragma unroll
            for (int q = 0; q < 4; q++)
                *(u16x8*)&Bsm[sr][cg + q*8] = *(const u16x8*)&src[q*8];
        }
        {
            int s = t & 63, pg = t >> 6;
            const u16* src = &xconv[(rowbase + st*64 + s) * D_INNER + h*HEAD_DIM + pg*16];
            u16x8 v0 = *(const u16x8*)&src[0];
            u16x8 v1 = *(const u16x8*)&src[8];
            #pragma unroll
            for (int q = 0; q < 8; q++) { xt[pg*16 + q][s] = v0[q]; xt[pg*16 + 8 + q][s] = v1[q]; }
        }
        __syncthreads();

        f32x4 sacc[4][4];
        #pragma unroll
        for (int i = 0; i < 4; i++)
            #pragma unroll
            for (int js = 0; js < 4; js++) sacc[i][js] = (f32x4){0.f,0.f,0.f,0.f};
        #pragma unroll
        for (int kk = 0; kk < 4; kk++) {
            bf16x8 bfr[4];
            #pragma unroll
            for (int js = 0; js < 4; js++)
                bfr[js] = *(const bf16x8*)&Bsm[js*16 + lr][kk*32 + kh*8];
            #pragma unroll
            for (int i = 0; i < 4; i++)
                #pragma unroll
                for (int js = 0; js < 4; js++)
                    sacc[i][js] = __builtin_amdgcn_mfma_f32_16x16x32_bf16(af[i][kk], bfr[js], sacc[i][js], 0, 0, 0);
        }
        #pragma unroll
        for (int i = 0; i < 4; i++) {
            #pragma unroll
            for (int js = 0; js < 4; js++) {
                int sl = js*16 + lr;
                int sg = st*64 + sl;
                float as = acs_sh[sg], ds = dt_sh[sg];
                #pragma unroll
                for (int q = 0; q < 4; q++) {
                    int l = w*64 + i*16 + kh*4 + q;
                    float arg = fminf(acs_sh[l] - as, 0.f);
                    float fac = (sg <= l) ? expf(arg) * ds : 0.f;
                    Pt[w][i*16 + kh*4 + q][sl] = f2us(sacc[i][js][q] * fac);
                }
            }
        }
        #pragma unroll
        for (int kk2 = 0; kk2 < 2; kk2++) {
            bf16x8 pa[4], xb[4];
            #pragma unroll
            for (int i = 0; i < 4; i++)
                pa[i] = *(const bf16x8*)&Pt[w][i*16 + lr][kk2*32 + kh*8];
            #pragma unroll
            for (int j = 0; j < 4; j++)
                xb[j] = *(const bf16x8*)&xt[j*16 + lr][kk2*32 + kh*8];
            #pragma unroll
            for (int i = 0; i < 4; i++)
                #pragma unroll
                for (int j = 0; j < 4; j++)
                    yacc[i][j] = __builtin_amdgcn_mfma_f32_16x16x32_bf16(pa[i], xb[j], yacc[i][j], 0, 0, 0);
        }
    }

    __syncthreads();
    {
        int p = t >> 2, ng = (t & 3) * 32;
        const float* src = &states[((size_t)((b*NCHUNK + c)*NHEADS + h)) * 8192 + (size_t)p * 128 + ng];
        #pragma unroll
        for (int q = 0; q < 4; q++) {
            float4 v0 = *(const float4*)&src[q*8];
            float4 v1 = *(const float4*)&src[q*8 + 4];
            u16x8 o;
            o[0]=f2us(v0.x); o[1]=f2us(v0.y); o[2]=f2us(v0.z); o[3]=f2us(v0.w);
            o[4]=f2us(v1.x); o[5]=f2us(v1.y); o[6]=f2us(v1.z); o[7]=f2us(v1.w);
            *(u16x8*)&Bsm[p][ng + q*8] = o;
        }
    }
    __syncthreads();
    {
        float el[4];
        #pragma unroll
        for (int i = 0; i < 4; i++) el[i] = expf(acs_sh[w*64 + i*16 + lr]);
        #pragma unroll
        for (int kk = 0; kk < 4; kk++) {
            bf16x8 pvf[4];
            #pragma unroll
            for (int j = 0; j < 4; j++)
                pvf[j] = *(const bf16x8*)&Bsm[j*16 + lr][kk*32 + kh*8];
            #pragma unroll
            for (int i = 0; i < 4; i++) {
                bf16x8 ae;
                #pragma unroll
                for (int e = 0; e < 8; e++)
                    ae[e] = (short)f2us(us2f((u16)af[i][kk][e]) * el[i]);
                #pragma unroll
                for (int j = 0; j < 4; j++)
                    yacc[i][j] = __builtin_amdgcn_mfma_f32_16x16x32_bf16(ae, pvf[j], yacc[i][j], 0, 0, 0);
            }
        }
    }

    float Dh = Dparam[h];
    #pragma unroll
    for (int i = 0; i < 4; i++) {
        #pragma unroll
        for (int j = 0; j < 4; j++) {
            #pragma unroll
            for (int q = 0; q < 4; q++) {
                int l = w*64 + i*16 + kh*4 + q;
                int p = j*16 + lr;
                size_t o = (rowbase + l) * D_INNER + h*HEAD_DIM + p;
                float v = yacc[i][j][q] + Dh * us2f(xconv[o]);
                Y[o] = f2us(v);
            }
        }
    }
}

// ---------------- gated RMSNorm ----------------
__global__ __launch_bounds__(256)
void gated_rmsnorm_k(u16* __restrict__ Y, const u16* __restrict__ zx,
                     const float* __restrict__ nw)
{
    __shared__ float xs[D_INNER];
    __shared__ float red[8];
    int row = blockIdx.x;
    int t = threadIdx.x;
    float ss = 0.f;
    for (int i = t*8; i < D_INNER; i += 2048) {
        u16x8 yv = *(const u16x8*)&Y[(size_t)row * D_INNER + i];
        u16x8 zv = *(const u16x8*)&zx[(size_t)row * LD_ZX + i];
        #pragma unroll
        for (int q = 0; q < 8; q++) {
            float x = us2f(yv[q]) * siluf(us2f(zv[q]));
            xs[i + q] = x;
            ss += x * x;
        }
    }
    #pragma unroll
    for (int off = 32; off > 0; off >>= 1) ss += __shfl_down(ss, off);
    int wid = t >> 6, lane = t & 63;
    if (lane == 0) red[wid] = ss;
    __syncthreads();
    if (t == 0) {
        float tot = red[0] + red[1] + red[2] + red[3];
        red[0] = rsqrtf(tot / (float)D_INNER + EPS_RMS);
    }
    __syncthreads();
    float sc = red[0];
    for (int i = t*8; i < D_INNER; i += 2048) {
        u16x8 o;
        #pragma unroll
        for (int q = 0; q < 8; q++) o[q] = f2us(xs[i + q] * sc * nw[i + q]);
        *(u16x8*)&Y[(size_t)row * D_INNER + i] = o;
    }
}

__global__ void ws_fail_k(float* out, float mb){ out[threadIdx.x] = mb; }

// ---------------- launch ----------------
extern "C" void kernel_launch(void* const* d_in, const int* in_sizes, int n_in,
                              void* d_out, int out_size, void* d_ws, size_t ws_size,
                              hipStream_t stream)
{
    const float* hidden  = (const float*)d_in[0];
    const float* W_in    = (const float*)d_in[1];
    const float* conv_w  = (const float*)d_in[2];
    const float* conv_b  = (const float*)d_in[3];
    const float* Aparam  = (const float*)d_in[4];
    const float* Dparam  = (const float*)d_in[5];
    const float* dt_bias = (const float*)d_in[6];
    const float* norm_w  = (const float*)d_in[7];
    const float* W_out   = (const float*)d_in[8];
    float* out = (float*)d_out;

    const int M = BATCH * SEQ;  // 4096

    size_t off = 0;
    char* wsb = (char*)d_ws;
    u16*   zx     = (u16*)  (wsb + off); off += (size_t)M * LD_ZX * 2;
    u16*   xconv  = (u16*)  (wsb + off); off += (size_t)M * D_INNER * 2;
    u16*   Bbuf   = (u16*)  (wsb + off); off += (size_t)M * D_STATE * 2;
    u16*   Cbuf   = (u16*)  (wsb + off); off += (size_t)M * D_STATE * 2;
    float* dtT    = (float*)(wsb + off); off += (size_t)BATCH * NHEADS * SEQ * 4;
    float* Acs    = (float*)(wsb + off); off += (size_t)BATCH * NHEADS * SEQ * 4;
    float* states = (float*)(wsb + off); off += (size_t)BATCH * NCHUNK * NHEADS * HEAD_DIM * D_STATE * 4;
    u16*   Ybuf   = (u16*)  (wsb + off); off += (size_t)M * D_INNER * 2;
    u16*   hbf    = (u16*)  (wsb + off); off += (size_t)M * D_MODEL * 2;
    u16*   WtIn   = (u16*)  (wsb + off); off += (size_t)LD_ZX * D_MODEL * 2;
    u16*   WtOut  = (u16*)  (wsb + off); off += (size_t)D_MODEL * D_INNER * 2;

    if (off > ws_size) {
        ws_fail_k<<<1, 64, 0, stream>>>(out, (float)(ws_size >> 20));
        return;
    }

    cvt_bf16<<<(M * D_MODEL / 4 + 255) / 256, 256, 0, stream>>>(hidden, hbf, M * D_MODEL / 4);
    transpose_cvt<<<dim3(D_MODEL/64, LD_ZX/64), 256, 0, stream>>>(W_in, WtIn, D_MODEL, D_IN_PROJ);
    transpose_cvt<<<dim3(D_INNER/64, D_MODEL/64), 256, 0, stream>>>(W_out, WtOut, D_INNER, D_MODEL);

    // GEMM1: zx[M, LD_ZX] = hbf @ WtIn^T   (K = 2048, NT = 32) — 8-phase + T2 swizzle
    gemm_8ph<u16><<<(LD_ZX/256) * (M/256), 512, 0, stream>>>(hbf, WtIn, zx, M, LD_ZX, D_MODEL, LD_ZX);

    conv_silu<<<(M * CONV_DIM / 8) / 256, 256, 0, stream>>>(zx, conv_w, conv_b, xconv, Bbuf, Cbuf);
    dt_acs<<<BATCH * NHEADS * NCHUNK, 256, 0, stream>>>(zx, Aparam, dt_bias, dtT, Acs);
    chunk_states_mfma<<<BATCH * NCHUNK * NHEADS, 256, 0, stream>>>(xconv, Bbuf, dtT, Acs, states);
    state_recurrence<<<(BATCH * NHEADS * HEAD_DIM * D_STATE) / 256, 256, 0, stream>>>(states, Acs);
    chunk_output_mfma<<<BATCH * NCHUNK * NHEADS, 256, 0, stream>>>(xconv, Bbuf, Cbuf, dtT, Acs, states, Dparam, Ybuf);
    gated_rmsnorm_k<<<M, 256, 0, stream>>>(Ybuf, zx, norm_w);

    // GEMM2: out[M, D_MODEL] = Ybuf @ WtOut^T  (K = 4096) — 2-phase 128² (512 blocks)
    gemm_mfma<float><<<dim3(D_MODEL/128, M/128), 256, 0, stream>>>(Ybuf, WtOut, out, M, D_MODEL, D_INNER, D_MODEL);
}

// Round 10
// 585.403 us; speedup vs baseline: 1.0227x; 1.0227x over previous
//
#include <hip/hip_runtime.h>
#include <hip/hip_bf16.h>
#include <math.h>

#define D_MODEL   2048
#define D_INNER   4096
#define NHEADS    64
#define HEAD_DIM  64
#define D_STATE   128
#define CHUNK     256
#define CONV_DIM  (D_INNER + 2*D_STATE)            // 4352
#define D_IN_PROJ (2*D_INNER + 2*D_STATE + NHEADS) // 8512
#define LD_ZX     8704                             // D_IN_PROJ padded to 256
#define DT_OFF    (2*D_INNER + 2*D_STATE)          // 8448
#define BATCH     2
#define SEQ       2048
#define NCHUNK    (SEQ/CHUNK)                      // 8
#define EPS_RMS   1e-5f

typedef unsigned short u16;
typedef __attribute__((ext_vector_type(8))) unsigned short u16x8;
typedef __attribute__((ext_vector_type(4))) unsigned short u16x4;
typedef __attribute__((ext_vector_type(8))) short bf16x8;   // MFMA A/B frag (8 bf16)
typedef __attribute__((ext_vector_type(4))) float f32x4;    // MFMA C/D frag

__device__ __forceinline__ float us2f(u16 u){
    union { unsigned int i; float f; } c; c.i = ((unsigned int)u) << 16; return c.f;
}
__device__ __forceinline__ u16 f2us(float f){
    union { float f; unsigned int i; } c; c.f = f;
    unsigned int r = c.i + 0x7FFFu + ((c.i >> 16) & 1u);
    return (u16)(r >> 16);
}
__device__ __forceinline__ float siluf(float x){ return x / (1.f + expf(-x)); }

__device__ __forceinline__ void gload_lds16(const void* g, void* l) {
    __builtin_amdgcn_global_load_lds((const __attribute__((address_space(1))) void*)g,
                                     (__attribute__((address_space(3))) void*)l, 16, 0, 0);
}

#define VMCNT(n) asm volatile("s_waitcnt vmcnt(" #n ")" ::: "memory")

// stage one 128x64 bf16 half-tile (row-major, stride ldk) into LDS with T2 swizzle.
// LDS dest stays LINEAR (gload_lds requirement); the SOURCE 16B-chunk index is
// permuted within each row (chunk ^= (chunk>>3)&7)  <->  read col ^= (row&7)<<3.
__device__ __forceinline__ void stage_half(const u16* __restrict__ g, size_t ldk,
                                           u16* ldsbase, int w, int lane)
{
    #pragma unroll
    for (int cc = 0; cc < 2; cc++) {
        int cb = cc * 512 + w * 64;          // wave-uniform chunk base
        int ci = cb + lane;
        int sc = ci ^ ((ci >> 3) & 7);       // swizzled source chunk (involution)
        gload_lds16(&g[(size_t)(sc >> 3) * ldk + (sc & 7) * 8], ldsbase + cb * 8);
    }
}

// ---------- elementwise f32 -> bf16 ----------
__global__ __launch_bounds__(256)
void cvt_bf16(const float* __restrict__ in, u16* __restrict__ out, int n4)
{
    int i = blockIdx.x * 256 + threadIdx.x;
    if (i >= n4) return;
    float4 v = *(const float4*)&in[(size_t)i * 4];
    u16x4 o; o[0]=f2us(v.x); o[1]=f2us(v.y); o[2]=f2us(v.z); o[3]=f2us(v.w);
    *(u16x4*)&out[(size_t)i * 4] = o;
}

// ---------- out += tmp (f32, vectorized) ----------
__global__ __launch_bounds__(256)
void add_f32(float* __restrict__ out, const float* __restrict__ tmp, int n4)
{
    int i = blockIdx.x * 256 + threadIdx.x;
    if (i >= n4) return;
    float4 a = *(const float4*)&out[(size_t)i * 4];
    float4 b = *(const float4*)&tmp[(size_t)i * 4];
    *(float4*)&out[(size_t)i * 4] = make_float4(a.x+b.x, a.y+b.y, a.z+b.z, a.w+b.w);
}

// ---------- transpose + convert: in f32 [K][N] -> out bf16 [Npad][K], zero-pad n>=N ----------
__global__ __launch_bounds__(256)
void transpose_cvt(const float* __restrict__ in, u16* __restrict__ out, int K, int N)
{
    __shared__ u16 tile[64][65];
    int k0 = blockIdx.x * 64;
    int n0 = blockIdx.y * 64;
    int t = threadIdx.x;
    #pragma unroll
    for (int q = 0; q < 16; q++) {
        int lin = q * 256 + t;
        int r = lin >> 6, c = lin & 63;
        int n = n0 + c;
        float v = (n < N) ? in[(size_t)(k0 + r) * N + n] : 0.f;
        tile[r][c] = f2us(v);
    }
    __syncthreads();
    #pragma unroll
    for (int q = 0; q < 16; q++) {
        int lin = q * 256 + t;
        int r = lin >> 6, c = lin & 63;
        out[(size_t)(n0 + r) * K + k0 + c] = tile[c][r];
    }
}

// ---------- 8-phase 256x256 MFMA GEMM (T2-swizzled LDS, plain barriers) ----------
// 512 thr = 8 waves (2M x 4N); per-wave C = 128x64; BK=64, dbuf LDS 128 KiB.
// Stage ledger (round-7 proven): p1: Ah1(t+1); p3: Bh0(t+2); p4: Bh1(t+2)+Ah0(t+2).
// Each A half-tile is read at BOTH p1 (rows 0-63) and p3 (rows 64-127) -> Ah0(t+2)
// may only be staged at p4. vmcnt(6) after p4 MFMA waits on exactly tile t+1's 4 halves.
// KSPLIT mode: grid = 2*ntiles; kidx = blockIdx&1 selects K-half (offset kidx*Kext in the
// row, stride ldk); kidx=1 writes Cg2. Used for GEMM2 (256 blocks = exactly 1 CU-round).
template<typename TC, bool KSPLIT>
__global__ __launch_bounds__(512, 1)
void gemm_8ph(const u16* __restrict__ Ag, const u16* __restrict__ Btg,
              TC* __restrict__ Cg, TC* __restrict__ Cg2,
              int M, int N, int Kext, int ldk, int ldc)
{
    __shared__ u16 smA[2][2][8192];   // [dbuf][half][128*64]
    __shared__ u16 smB[2][2][8192];
    const int tid = threadIdx.x;
    const int lane = tid & 63, w = tid >> 6;
    const int wm = w >> 2, wn = w & 3;
    const int lr = lane & 15, kh = lane >> 4;
    const int swz = (lr & 7) << 3;     // read-side T2 swizzle (all frag rows ≡ lr mod 8)

    int orig = blockIdx.x;
    int ntile = gridDim.x;
    int kidx = 0;
    if constexpr (KSPLIT) { kidx = orig & 1; orig >>= 1; ntile >>= 1; }

    // bijective XCD swizzle (m204) over tiles
    const int nbx = N >> 8;
    const int qq = ntile >> 3, r8 = ntile & 7;
    const int xcd = orig & 7, loc = orig >> 3;
    const int wgid = (xcd < r8 ? xcd*(qq+1) : r8*(qq+1) + (xcd-r8)*qq) + loc;
    const int m0 = (wgid / nbx) * 256;
    const int n0 = (wgid % nbx) * 256;

    if constexpr (KSPLIT) {
        Ag  += (size_t)kidx * Kext;
        Btg += (size_t)kidx * Kext;
        if (kidx) Cg = Cg2;
    }
    const int NT = Kext >> 6;

    f32x4 acc[8][4];
    #pragma unroll
    for (int i = 0; i < 8; i++)
        #pragma unroll
        for (int j = 0; j < 4; j++) acc[i][j] = (f32x4){0.f,0.f,0.f,0.f};

    // ---- prologue: tile0 {Ah0,Ah1,Bh0,Bh1} + tile1 {Ah0,Bh0,Bh1}; vmcnt(6) -> tile0 ready
    stage_half(&Ag [(size_t)(m0      ) * ldk      ], ldk, &smA[0][0][0], w, lane);
    stage_half(&Ag [(size_t)(m0 + 128) * ldk      ], ldk, &smA[0][1][0], w, lane);
    stage_half(&Btg[(size_t)(n0      ) * ldk      ], ldk, &smB[0][0][0], w, lane);
    stage_half(&Btg[(size_t)(n0 + 128) * ldk      ], ldk, &smB[0][1][0], w, lane);
    stage_half(&Ag [(size_t)(m0      ) * ldk + 64 ], ldk, &smA[1][0][0], w, lane);
    stage_half(&Btg[(size_t)(n0      ) * ldk + 64 ], ldk, &smB[1][0][0], w, lane);
    stage_half(&Btg[(size_t)(n0 + 128) * ldk + 64 ], ldk, &smB[1][1][0], w, lane);
    VMCNT(6);
    __builtin_amdgcn_s_barrier();

    for (int t = 0; t < NT; ++t) {
        const int d = t & 1;
        const u16* As = &smA[d][wm][0];
        const u16* Bs = &smB[d][wn >> 1][0];
        const int rb = (wn & 1) * 64;

        bf16x8 aF[4][2], bLo[2][2], bHi[2][2];

        // ---- phase 1: read A-lo + B-lo; stage Ah1(t+1)
        #pragma unroll
        for (int i = 0; i < 4; i++)
            #pragma unroll
            for (int ks = 0; ks < 2; ks++)
                aF[i][ks] = *(const bf16x8*)&As[(i*16 + lr)*64 + ((ks*32 + kh*8) ^ swz)];
        #pragma unroll
        for (int j = 0; j < 2; j++)
            #pragma unroll
            for (int ks = 0; ks < 2; ks++)
                bLo[j][ks] = *(const bf16x8*)&Bs[(rb + j*16 + lr)*64 + ((ks*32 + kh*8) ^ swz)];
        if (t + 1 < NT)
            stage_half(&Ag[(size_t)(m0 + 128) * ldk + (t+1)*64], ldk, &smA[d^1][1][0], w, lane);
        __builtin_amdgcn_s_barrier();
        __builtin_amdgcn_s_setprio(1);
        #pragma unroll
        for (int i = 0; i < 4; i++)
            #pragma unroll
            for (int j = 0; j < 2; j++)
                #pragma unroll
                for (int ks = 0; ks < 2; ks++)
                    acc[i][j] = __builtin_amdgcn_mfma_f32_16x16x32_bf16(aF[i][ks], bLo[j][ks], acc[i][j], 0, 0, 0);
        __builtin_amdgcn_s_setprio(0);
        __builtin_amdgcn_s_barrier();

        // ---- phase 2: read B-hi (no staging; smA[d][0] still read at p3)
        #pragma unroll
        for (int j = 0; j < 2; j++)
            #pragma unroll
            for (int ks = 0; ks < 2; ks++)
                bHi[j][ks] = *(const bf16x8*)&Bs[(rb + (2+j)*16 + lr)*64 + ((ks*32 + kh*8) ^ swz)];
        __builtin_amdgcn_s_barrier();
        __builtin_amdgcn_s_setprio(1);
        #pragma unroll
        for (int i = 0; i < 4; i++)
            #pragma unroll
            for (int j = 0; j < 2; j++)
                #pragma unroll
                for (int ks = 0; ks < 2; ks++)
                    acc[i][2+j] = __builtin_amdgcn_mfma_f32_16x16x32_bf16(aF[i][ks], bHi[j][ks], acc[i][2+j], 0, 0, 0);
        __builtin_amdgcn_s_setprio(0);
        __builtin_amdgcn_s_barrier();

        // ---- phase 3: read A-hi (overwrites aF); stage Bh0(t+2)  (B-hi LDS read done at p2)
        #pragma unroll
        for (int i = 0; i < 4; i++)
            #pragma unroll
            for (int ks = 0; ks < 2; ks++)
                aF[i][ks] = *(const bf16x8*)&As[(64 + i*16 + lr)*64 + ((ks*32 + kh*8) ^ swz)];
        if (t + 2 < NT)
            stage_half(&Btg[(size_t)(n0) * ldk + (t+2)*64], ldk, &smB[d][0][0], w, lane);
        __builtin_amdgcn_s_barrier();
        __builtin_amdgcn_s_setprio(1);
        #pragma unroll
        for (int i = 0; i < 4; i++)
            #pragma unroll
            for (int j = 0; j < 2; j++)
                #pragma unroll
                for (int ks = 0; ks < 2; ks++)
                    acc[4+i][j] = __builtin_amdgcn_mfma_f32_16x16x32_bf16(aF[i][ks], bLo[j][ks], acc[4+i][j], 0, 0, 0);
        __builtin_amdgcn_s_setprio(0);
        __builtin_amdgcn_s_barrier();

        // ---- phase 4: stage Bh1(t+2)+Ah0(t+2) (A's last read was p3); MFMA; counted vmcnt after
        if (t + 2 < NT) {
            stage_half(&Btg[(size_t)(n0 + 128) * ldk + (t+2)*64], ldk, &smB[d][1][0], w, lane);
            stage_half(&Ag [(size_t)(m0      ) * ldk + (t+2)*64], ldk, &smA[d][0][0], w, lane);
        }
        __builtin_amdgcn_s_barrier();
        __builtin_amdgcn_s_setprio(1);
        #pragma unroll
        for (int i = 0; i < 4; i++)
            #pragma unroll
            for (int j = 0; j < 2; j++)
                #pragma unroll
                for (int ks = 0; ks < 2; ks++)
                    acc[4+i][2+j] = __builtin_amdgcn_mfma_f32_16x16x32_bf16(aF[i][ks], bHi[j][ks], acc[4+i][2+j], 0, 0, 0);
        __builtin_amdgcn_s_setprio(0);
        if (t < NT - 2)       { VMCNT(6); }
        else if (t == NT - 2) { VMCNT(0); }
        __builtin_amdgcn_s_barrier();
    }

    // ---- epilogue
    #pragma unroll
    for (int mf = 0; mf < 8; mf++) {
        #pragma unroll
        for (int nf = 0; nf < 4; nf++) {
            int r = m0 + wm*128 + mf*16 + kh*4;
            int cidx = n0 + wn*64 + nf*16 + lr;
            #pragma unroll
            for (int q = 0; q < 4; q++) {
                if constexpr (sizeof(TC) == 4) Cg[(size_t)(r+q)*ldc + cidx] = acc[mf][nf][q];
                else                           Cg[(size_t)(r+q)*ldc + cidx] = f2us(acc[mf][nf][q]);
            }
        }
    }
}

// ---------- 2-phase 128x128 MFMA GEMM — used for GEMM1's N-tail ----------
template<typename TC>
__global__ __launch_bounds__(256)
void gemm_mfma(const u16* __restrict__ A, const u16* __restrict__ Bt,
               TC* __restrict__ C, int M, int N, int K, int ldc)
{
    __shared__ u16 Asm[128][32];   // 8 KB
    __shared__ u16 Bsm[128][32];   // 8 KB
    const int t = threadIdx.x;
    const int lane = t & 63, w = t >> 6;
    const int wr = w >> 1, wc = w & 1;
    const int lr = lane & 15, kh = lane >> 4;

    const int nwg = gridDim.x * gridDim.y;
    const int orig = blockIdx.y * gridDim.x + blockIdx.x;
    const int qq = nwg >> 3, r8 = nwg & 7;
    const int xcd = orig & 7, loc = orig >> 3;
    const int wgid = (xcd < r8 ? xcd*(qq+1) : r8*(qq+1) + (xcd-r8)*qq) + loc;
    const int m0 = (wgid / gridDim.x) * 128;
    const int n0 = (wgid % gridDim.x) * 128;

    f32x4 acc[4][4];
    #pragma unroll
    for (int i = 0; i < 4; i++)
        #pragma unroll
        for (int j = 0; j < 4; j++) acc[i][j] = (f32x4){0.f,0.f,0.f,0.f};

    for (int k0 = 0; k0 < K; k0 += 32) {
        #pragma unroll
        for (int i = 0; i < 2; i++) {
            int cb = i * 256 + w * 64;
            int chunk = cb + lane;
            int row = chunk >> 2, kb = chunk & 3;
            gload_lds16(&A[(size_t)(m0 + row) * K + k0 + kb * 8], &Asm[0][0] + cb * 8);
            gload_lds16(&Bt[(size_t)(n0 + row) * K + k0 + kb * 8], &Bsm[0][0] + cb * 8);
        }
        __syncthreads();
        bf16x8 af[4], bf[4];
        #pragma unroll
        for (int i = 0; i < 4; i++)
            af[i] = *(const bf16x8*)&Asm[wr*64 + i*16 + lr][kh*8];
        #pragma unroll
        for (int j = 0; j < 4; j++)
            bf[j] = *(const bf16x8*)&Bsm[wc*64 + j*16 + lr][kh*8];
        #pragma unroll
        for (int i = 0; i < 4; i++)
            #pragma unroll
            for (int j = 0; j < 4; j++)
                acc[i][j] = __builtin_amdgcn_mfma_f32_16x16x32_bf16(af[i], bf[j], acc[i][j], 0, 0, 0);
        __syncthreads();
    }
    #pragma unroll
    for (int i = 0; i < 4; i++) {
        #pragma unroll
        for (int j = 0; j < 4; j++) {
            int r = m0 + wr*64 + i*16 + kh*4;
            int cidx = n0 + wc*64 + j*16 + lr;
            #pragma unroll
            for (int q = 0; q < 4; q++) {
                if constexpr (sizeof(TC) == 4) C[(size_t)(r+q)*ldc + cidx] = acc[i][j][q];
                else                           C[(size_t)(r+q)*ldc + cidx] = f2us(acc[i][j][q]);
            }
        }
    }
}

// ---------------- conv1d (K=4) + bias + SiLU, 8 channels/thread ----------------
__global__ __launch_bounds__(256)
void conv_silu(const u16* __restrict__ zx, const float* __restrict__ cw,
               const float* __restrict__ cb, u16* __restrict__ xconv,
               u16* __restrict__ Bbuf, u16* __restrict__ Cbuf)
{
    int idx = blockIdx.x * 256 + threadIdx.x;        // < M * (CONV_DIM/8)
    int cg = idx % (CONV_DIM / 8);
    int r  = idx / (CONV_DIM / 8);
    int c0 = cg * 8;
    int l  = r & (SEQ - 1);

    float y[8];
    {
        float4 b0 = *(const float4*)&cb[c0];
        float4 b1 = *(const float4*)&cb[c0 + 4];
        y[0]=b0.x; y[1]=b0.y; y[2]=b0.z; y[3]=b0.w;
        y[4]=b1.x; y[5]=b1.y; y[6]=b1.z; y[7]=b1.w;
    }
    float cwf[8][4];
    #pragma unroll
    for (int e = 0; e < 8; e++) {
        float4 v = *(const float4*)&cw[(c0 + e) * 4];
        cwf[e][0]=v.x; cwf[e][1]=v.y; cwf[e][2]=v.z; cwf[e][3]=v.w;
    }
    #pragma unroll
    for (int k = 0; k < 4; k++) {
        if (l + k - 3 >= 0) {
            u16x8 v = *(const u16x8*)&zx[(size_t)(r + k - 3) * LD_ZX + D_INNER + c0];
            #pragma unroll
            for (int e = 0; e < 8; e++) y[e] += us2f(v[e]) * cwf[e][k];
        }
    }
    u16x8 o;
    #pragma unroll
    for (int e = 0; e < 8; e++) {
        float s = y[e] / (1.f + expf(-y[e]));
        o[e] = f2us(s);
    }
    if (c0 < D_INNER)                *(u16x8*)&xconv[(size_t)r * D_INNER + c0] = o;
    else if (c0 < D_INNER + D_STATE) *(u16x8*)&Bbuf[(size_t)r * D_STATE + (c0 - D_INNER)] = o;
    else                             *(u16x8*)&Cbuf[(size_t)r * D_STATE + (c0 - D_INNER - D_STATE)] = o;
}

// ---------------- dt softplus + per-chunk cumsum ----------------
__global__ __launch_bounds__(256)
void dt_acs(const u16* __restrict__ zx, const float* __restrict__ Aparam,
            const float* __restrict__ dt_bias, float* __restrict__ dtT,
            float* __restrict__ Acs)
{
    __shared__ float sb[CHUNK];
    int blk = blockIdx.x;
    int c = blk & 7, h = (blk >> 3) & 63, b = blk >> 9;
    int t = threadIdx.x;
    int lg = c * CHUNK + t;
    int row = b * SEQ + lg;
    float x = us2f(zx[(size_t)row * LD_ZX + DT_OFF + h]) + dt_bias[h];
    float dt = (x > 20.f) ? x : log1pf(expf(x));
    float v = dt * Aparam[h];
    sb[t] = v; __syncthreads();
    #pragma unroll
    for (int off = 1; off < 256; off <<= 1) {
        float add = (t >= off) ? sb[t - off] : 0.f;
        __syncthreads();
        v += add; sb[t] = v;
        __syncthreads();
    }
    int o = (b * NHEADS + h) * SEQ + lg;
    dtT[o] = dt;
    Acs[o] = v;
}

// ---------------- per-chunk states via MFMA ----------------
__global__ __launch_bounds__(256)
void chunk_states_mfma(const u16* __restrict__ xconv, const u16* __restrict__ Bbuf,
                       const float* __restrict__ dtT, const float* __restrict__ Acs,
                       float* __restrict__ states)
{
    __shared__ u16 Btsh[128][72];
    __shared__ u16 xtsh[64][72];
    __shared__ float acs_sh[CHUNK];
    __shared__ float dt_sh[CHUNK];

    const int blk = blockIdx.x;
    const int h = blk & 63, c = (blk >> 6) & 7, b = blk >> 9;
    const int t = threadIdx.x;
    const int lane = t & 63, w = t >> 6;
    const int wr = w >> 1, wc = w & 1;
    const int lr = lane & 15, kh = lane >> 4;
    const int bh = b * NHEADS + h;
    const size_t rowbase = (size_t)(b * SEQ + c * CHUNK);

    acs_sh[t] = Acs[(size_t)bh * SEQ + c * CHUNK + t];
    dt_sh[t]  = dtT[(size_t)bh * SEQ + c * CHUNK + t];
    __syncthreads();
    const float acs_last = acs_sh[CHUNK - 1];

    f32x4 acc[2][4];
    #pragma unroll
    for (int i = 0; i < 2; i++)
        #pragma unroll
        for (int j = 0; j < 4; j++) acc[i][j] = (f32x4){0.f,0.f,0.f,0.f};

    for (int lt = 0; lt < 4; lt++) {
        __syncthreads();
        const int s = t & 63;
        const int sg = lt * 64 + s;
        const float wgt = dt_sh[sg] * expf(acs_last - acs_sh[sg]);
        {
            int ng = (t >> 6) * 32;
            const u16* src = &Bbuf[(rowbase + sg) * D_STATE + ng];
            #pragma unroll
            for (int q = 0; q < 4; q++) {
                u16x8 v = *(const u16x8*)&src[q * 8];
                #pragma unroll
                for (int e = 0; e < 8; e++)
                    Btsh[ng + q*8 + e][s] = f2us(us2f(v[e]) * wgt);
            }
        }
        {
            int pg = (t >> 6) * 16;
            const u16* src = &xconv[(rowbase + sg) * D_INNER + h * HEAD_DIM + pg];
            u16x8 v0 = *(const u16x8*)&src[0];
            u16x8 v1 = *(const u16x8*)&src[8];
            #pragma unroll
            for (int e = 0; e < 8; e++) { xtsh[pg + e][s] = v0[e]; xtsh[pg + 8 + e][s] = v1[e]; }
        }
        __syncthreads();
        #pragma unroll
        for (int kk = 0; kk < 2; kk++) {
            bf16x8 af[2], bf[4];
            #pragma unroll
            for (int i = 0; i < 2; i++)
                af[i] = *(const bf16x8*)&xtsh[wr*32 + i*16 + lr][kk*32 + kh*8];
            #pragma unroll
            for (int j = 0; j < 4; j++)
                bf[j] = *(const bf16x8*)&Btsh[wc*64 + j*16 + lr][kk*32 + kh*8];
            #pragma unroll
            for (int i = 0; i < 2; i++)
                #pragma unroll
                for (int j = 0; j < 4; j++)
                    acc[i][j] = __builtin_amdgcn_mfma_f32_16x16x32_bf16(af[i], bf[j], acc[i][j], 0, 0, 0);
        }
    }
    size_t base = ((size_t)((b*NCHUNK + c)*NHEADS + h)) * (HEAD_DIM * D_STATE);
    #pragma unroll
    for (int i = 0; i < 2; i++) {
        #pragma unroll
        for (int j = 0; j < 4; j++) {
            int p = wr*32 + i*16 + kh*4;
            int n = wc*64 + j*16 + lr;
            #pragma unroll
            for (int q = 0; q < 4; q++)
                states[base + (size_t)(p + q) * D_STATE + n] = acc[i][j][q];
        }
    }
}

// ---------------- inter-chunk recurrence ----------------
__global__ __launch_bounds__(256)
void state_recurrence(float* __restrict__ states, const float* __restrict__ Acs)
{
    int idx = blockIdx.x * 256 + threadIdx.x;
    int pn = idx & 8191;
    int bh = idx >> 13;
    int b = bh >> 6, h = bh & 63;
    float E = 0.f;
    for (int c = 0; c < NCHUNK; c++) {
        size_t off = ((size_t)((b*NCHUNK + c)*NHEADS + h)) * 8192 + pn;
        float s = states[off];
        states[off] = E;
        float cs = Acs[(size_t)(b*NHEADS + h) * SEQ + c*CHUNK + 255];
        E = expf(cs) * E + s;
    }
}

// ---------------- chunk output, MFMA ----------------
__global__ __launch_bounds__(256, 1)
void chunk_output_mfma(const u16* __restrict__ xconv, const u16* __restrict__ Bbuf,
                       const u16* __restrict__ Cbuf, const float* __restrict__ dtT,
                       const float* __restrict__ Acs, const float* __restrict__ states,
                       const float* __restrict__ Dparam, u16* __restrict__ Y)
{
    __shared__ u16 Bsm[64][130];
    __shared__ u16 xt[64][66];
    __shared__ u16 Pt[4][64][66];
    __shared__ float acs_sh[CHUNK];
    __shared__ float dt_sh[CHUNK];

    const int blk = blockIdx.x;
    const int h = blk & 63, c = (blk >> 6) & 7, b = blk >> 9;
    const int t = threadIdx.x;
    const int lane = t & 63, w = t >> 6;
    const int lr = lane & 15, kh = lane >> 4;
    const int bh = b * NHEADS + h;
    const size_t rowbase = (size_t)(b * SEQ + c * CHUNK);

    acs_sh[t] = Acs[(size_t)bh * SEQ + c * CHUNK + t];
    dt_sh[t]  = dtT[(size_t)bh * SEQ + c * CHUNK + t];

    bf16x8 af[4][4];
    #pragma unroll
    for (int i = 0; i < 4; i++)
        #pragma unroll
        for (int kk = 0; kk < 4; kk++)
            af[i][kk] = *(const bf16x8*)&Cbuf[(rowbase + w*64 + i*16 + lr) * D_STATE + kk*32 + kh*8];

    f32x4 yacc[4][4];
    #pragma unroll
    for (int i = 0; i < 4; i++)
        #pragma unroll
        for (int j = 0; j < 4; j++) yacc[i][j] = (f32x4){0.f,0.f,0.f,0.f};

    for (int st = 0; st < 4; st++) {
        __syncthreads();
        {
            int sr = t >> 2, cg = (t & 3) * 32;
            const u16* src = &Bbuf[(rowbase + st*64 + sr) * D_STATE + cg];
            #pragma unroll
            for (int q = 0; q < 4; q++)
                *(u16x8*)&Bsm[sr][cg + q*8] = *(const u16x8*)&src[q*8];
        }
        {
            int s = t & 63, pg = t >> 6;
            const u16* src = &xconv[(rowbase + st*64 + s) * D_INNER + h*HEAD_DIM + pg*16];
            u16x8 v0 = *(const u16x8*)&src[0];
            u16x8 v1 = *(const u16x8*)&src[8];
            #pragma unroll
            for (int q = 0; q < 8; q++) { xt[pg*16 + q][s] = v0[q]; xt[pg*16 + 8 + q][s] = v1[q]; }
        }
        __syncthreads();

        f32x4 sacc[4][4];
        #pragma unroll
        for (int i = 0; i < 4; i++)
            #pragma unroll
            for (int js = 0; js < 4; js++) sacc[i][js] = (f32x4){0.f,0.f,0.f,0.f};
        #pragma unroll
        for (int kk = 0; kk < 4; kk++) {
            bf16x8 bfr[4];
            #pragma unroll
            for (int js = 0; js < 4; js++)
                bfr[js] = *(const bf16x8*)&Bsm[js*16 + lr][kk*32 + kh*8];
            #pragma unroll
            for (int i = 0; i < 4; i++)
                #pragma unroll
                for (int js = 0; js < 4; js++)
                    sacc[i][js] = __builtin_amdgcn_mfma_f32_16x16x32_bf16(af[i][kk], bfr[js], sacc[i][js], 0, 0, 0);
        }
        #pragma unroll
        for (int i = 0; i < 4; i++) {
            #pragma unroll
            for (int js = 0; js < 4; js++) {
                int sl = js*16 + lr;
                int sg = st*64 + sl;
                float as = acs_sh[sg], ds = dt_sh[sg];
                #pragma unroll
                for (int q = 0; q < 4; q++) {
                    int l = w*64 + i*16 + kh*4 + q;
                    float arg = fminf(acs_sh[l] - as, 0.f);
                    float fac = (sg <= l) ? expf(arg) * ds : 0.f;
                    Pt[w][i*16 + kh*4 + q][sl] = f2us(sacc[i][js][q] * fac);
                }
            }
        }
        #pragma unroll
        for (int kk2 = 0; kk2 < 2; kk2++) {
            bf16x8 pa[4], xb[4];
            #pragma unroll
            for (int i = 0; i < 4; i++)
                pa[i] = *(const bf16x8*)&Pt[w][i*16 + lr][kk2*32 + kh*8];
            #pragma unroll
            for (int j = 0; j < 4; j++)
                xb[j] = *(const bf16x8*)&xt[j*16 + lr][kk2*32 + kh*8];
            #pragma unroll
            for (int i = 0; i < 4; i++)
                #pragma unroll
                for (int j = 0; j < 4; j++)
                    yacc[i][j] = __builtin_amdgcn_mfma_f32_16x16x32_bf16(pa[i], xb[j], yacc[i][j], 0, 0, 0);
        }
    }

    __syncthreads();
    {
        int p = t >> 2, ng = (t & 3) * 32;
        const float* src = &states[((size_t)((b*NCHUNK + c)*NHEADS + h)) * 8192 + (size_t)p * 128 + ng];
        #pragma unroll
        for (int q = 0; q < 4; q++) {
            float4 v0 = *(const float4*)&src[q*8];
            float4 v1 = *(const float4*)&src[q*8 + 4];
            u16x8 o;
            o[0]=f2us(v0.x); o[1]=f2us(v0.y); o[2]=f2us(v0.z); o[3]=f2us(v0.w);
            o[4]=f2us(v1.x); o[5]=f2us(v1.y); o[6]=f2us(v1.z); o[7]=f2us(v1.w);
            *(u16x8*)&Bsm[p][ng + q*8] = o;
        }
    }
    __syncthreads();
    {
        float el[4];
        #pragma unroll
        for (int i = 0; i < 4; i++) el[i] = expf(acs_sh[w*64 + i*16 + lr]);
        #pragma unroll
        for (int kk = 0; kk < 4; kk++) {
            bf16x8 pvf[4];
            #pragma unroll
            for (int j = 0; j < 4; j++)
                pvf[j] = *(const bf16x8*)&Bsm[j*16 + lr][kk*32 + kh*8];
            #pragma unroll
            for (int i = 0; i < 4; i++) {
                bf16x8 ae;
                #pragma unroll
                for (int e = 0; e < 8; e++)
                    ae[e] = (short)f2us(us2f((u16)af[i][kk][e]) * el[i]);
                #pragma unroll
                for (int j = 0; j < 4; j++)
                    yacc[i][j] = __builtin_amdgcn_mfma_f32_16x16x32_bf16(ae, pvf[j], yacc[i][j], 0, 0, 0);
            }
        }
    }

    float Dh = Dparam[h];
    #pragma unroll
    for (int i = 0; i < 4; i++) {
        #pragma unroll
        for (int j = 0; j < 4; j++) {
            #pragma unroll
            for (int q = 0; q < 4; q++) {
                int l = w*64 + i*16 + kh*4 + q;
                int p = j*16 + lr;
                size_t o = (rowbase + l) * D_INNER + h*HEAD_DIM + p;
                float v = yacc[i][j][q] + Dh * us2f(xconv[o]);
                Y[o] = f2us(v);
            }
        }
    }
}

// ---------------- gated RMSNorm ----------------
__global__ __launch_bounds__(256)
void gated_rmsnorm_k(u16* __restrict__ Y, const u16* __restrict__ zx,
                     const float* __restrict__ nw)
{
    __shared__ float xs[D_INNER];
    __shared__ float red[8];
    int row = blockIdx.x;
    int t = threadIdx.x;
    float ss = 0.f;
    for (int i = t*8; i < D_INNER; i += 2048) {
        u16x8 yv = *(const u16x8*)&Y[(size_t)row * D_INNER + i];
        u16x8 zv = *(const u16x8*)&zx[(size_t)row * LD_ZX + i];
        #pragma unroll
        for (int q = 0; q < 8; q++) {
            float x = us2f(yv[q]) * siluf(us2f(zv[q]));
            xs[i + q] = x;
            ss += x * x;
        }
    }
    #pragma unroll
    for (int off = 32; off > 0; off >>= 1) ss += __shfl_down(ss, off);
    int wid = t >> 6, lane = t & 63;
    if (lane == 0) red[wid] = ss;
    __syncthreads();
    if (t == 0) {
        float tot = red[0] + red[1] + red[2] + red[3];
        red[0] = rsqrtf(tot / (float)D_INNER + EPS_RMS);
    }
    __syncthreads();
    float sc = red[0];
    for (int i = t*8; i < D_INNER; i += 2048) {
        u16x8 o;
        #pragma unroll
        for (int q = 0; q < 8; q++) o[q] = f2us(xs[i + q] * sc * nw[i + q]);
        *(u16x8*)&Y[(size_t)row * D_INNER + i] = o;
    }
}

__global__ void ws_fail_k(float* out, float mb){ out[threadIdx.x] = mb; }

// ---------------- launch ----------------
extern "C" void kernel_launch(void* const* d_in, const int* in_sizes, int n_in,
                              void* d_out, int out_size, void* d_ws, size_t ws_size,
                              hipStream_t stream)
{
    const float* hidden  = (const float*)d_in[0];
    const float* W_in    = (const float*)d_in[1];
    const float* conv_w  = (const float*)d_in[2];
    const float* conv_b  = (const float*)d_in[3];
    const float* Aparam  = (const float*)d_in[4];
    const float* Dparam  = (const float*)d_in[5];
    const float* dt_bias = (const float*)d_in[6];
    const float* norm_w  = (const float*)d_in[7];
    const float* W_out   = (const float*)d_in[8];
    float* out = (float*)d_out;

    const int M = BATCH * SEQ;  // 4096

    size_t off = 0;
    char* wsb = (char*)d_ws;
    u16*   zx     = (u16*)  (wsb + off); off += (size_t)M * LD_ZX * 2;
    u16*   xconv  = (u16*)  (wsb + off); off += (size_t)M * D_INNER * 2;
    u16*   Bbuf   = (u16*)  (wsb + off); off += (size_t)M * D_STATE * 2;
    u16*   Cbuf   = (u16*)  (wsb + off); off += (size_t)M * D_STATE * 2;
    float* dtT    = (float*)(wsb + off); off += (size_t)BATCH * NHEADS * SEQ * 4;
    float* Acs    = (float*)(wsb + off); off += (size_t)BATCH * NHEADS * SEQ * 4;
    float* states = (float*)(wsb + off); off += (size_t)BATCH * NCHUNK * NHEADS * HEAD_DIM * D_STATE * 4;
    u16*   Ybuf   = (u16*)  (wsb + off); off += (size_t)M * D_INNER * 2;
    u16*   hbf    = (u16*)  (wsb + off); off += (size_t)M * D_MODEL * 2;
    u16*   WtIn   = (u16*)  (wsb + off); off += (size_t)LD_ZX * D_MODEL * 2;
    u16*   WtOut  = (u16*)  (wsb + off); off += (size_t)D_MODEL * D_INNER * 2;
    // GEMM2 K-split partial buffer: aliases zx (dead after gated_rmsnorm, before GEMM2).
    float* tmpf   = (float*)zx;                 // 4096*2048*4 = 33.5 MB << zx's 71 MB

    if (off > ws_size) {
        ws_fail_k<<<1, 64, 0, stream>>>(out, (float)(ws_size >> 20));
        return;
    }

    cvt_bf16<<<(M * D_MODEL / 4 + 255) / 256, 256, 0, stream>>>(hidden, hbf, M * D_MODEL / 4);
    transpose_cvt<<<dim3(D_MODEL/64, LD_ZX/64), 256, 0, stream>>>(W_in, WtIn, D_MODEL, D_IN_PROJ);
    transpose_cvt<<<dim3(D_INNER/64, D_MODEL/64), 256, 0, stream>>>(W_out, WtOut, D_INNER, D_MODEL);

    // GEMM1 main: zx[:, 0:8192] — 512 blocks = exactly 2 CU-rounds (256 CUs, 1 blk/CU)
    gemm_8ph<u16, false><<<(8192/256) * (M/256), 512, 0, stream>>>(
        hbf, WtIn, zx, nullptr, M, 8192, D_MODEL, D_MODEL, LD_ZX);
    // GEMM1 tail: zx[:, 8192:8704] (rest of B/C + dt + pad) — 2-phase 128², 128 blocks
    gemm_mfma<u16><<<dim3(4, M/128), 256, 0, stream>>>(
        hbf, WtIn + (size_t)8192 * D_MODEL, zx + 8192, M, 512, D_MODEL, LD_ZX);

    conv_silu<<<(M * CONV_DIM / 8) / 256, 256, 0, stream>>>(zx, conv_w, conv_b, xconv, Bbuf, Cbuf);
    dt_acs<<<BATCH * NHEADS * NCHUNK, 256, 0, stream>>>(zx, Aparam, dt_bias, dtT, Acs);
    chunk_states_mfma<<<BATCH * NCHUNK * NHEADS, 256, 0, stream>>>(xconv, Bbuf, dtT, Acs, states);
    state_recurrence<<<(BATCH * NHEADS * HEAD_DIM * D_STATE) / 256, 256, 0, stream>>>(states, Acs);
    chunk_output_mfma<<<BATCH * NCHUNK * NHEADS, 256, 0, stream>>>(xconv, Bbuf, Cbuf, dtT, Acs, states, Dparam, Ybuf);
    gated_rmsnorm_k<<<M, 256, 0, stream>>>(Ybuf, zx, norm_w);   // last reader of zx

    // GEMM2 K-split-2: 128 tiles x 2 K-halves = 256 blocks = exactly 1 CU-round.
    // kidx=0 -> out (K[0,2048)), kidx=1 -> tmpf (K[2048,4096)); then out += tmpf.
    gemm_8ph<float, true><<<2 * (D_MODEL/256) * (M/256), 512, 0, stream>>>(
        Ybuf, WtOut, out, tmpf, M, D_MODEL, D_INNER/2, D_INNER, D_MODEL);
    add_f32<<<(M * D_MODEL / 4 + 255) / 256, 256, 0, stream>>>(out, tmpf, M * D_MODEL / 4);
}

// Round 11
// 565.945 us; speedup vs baseline: 1.0579x; 1.0344x over previous
//
#include <hip/hip_runtime.h>
#include <hip/hip_bf16.h>
#include <math.h>

#define D_MODEL   2048
#define D_INNER   4096
#define NHEADS    64
#define HEAD_DIM  64
#define D_STATE   128
#define CHUNK     256
#define CONV_DIM  (D_INNER + 2*D_STATE)            // 4352
#define D_IN_PROJ (2*D_INNER + 2*D_STATE + NHEADS) // 8512
#define LD_ZX     8704                             // D_IN_PROJ padded to 256
#define DT_OFF    (2*D_INNER + 2*D_STATE)          // 8448
#define BATCH     2
#define SEQ       2048
#define NCHUNK    (SEQ/CHUNK)                      // 8
#define EPS_RMS   1e-5f

typedef unsigned short u16;
typedef __attribute__((ext_vector_type(8))) unsigned short u16x8;
typedef __attribute__((ext_vector_type(4))) unsigned short u16x4;
typedef __attribute__((ext_vector_type(8))) short bf16x8;   // MFMA A/B frag (8 bf16)
typedef __attribute__((ext_vector_type(4))) float f32x4;    // MFMA C/D frag

__device__ __forceinline__ float us2f(u16 u){
    union { unsigned int i; float f; } c; c.i = ((unsigned int)u) << 16; return c.f;
}
__device__ __forceinline__ u16 f2us(float f){
    union { float f; unsigned int i; } c; c.f = f;
    unsigned int r = c.i + 0x7FFFu + ((c.i >> 16) & 1u);
    return (u16)(r >> 16);
}
__device__ __forceinline__ float siluf(float x){ return x / (1.f + expf(-x)); }

__device__ __forceinline__ void gload_lds16(const void* g, void* l) {
    __builtin_amdgcn_global_load_lds((const __attribute__((address_space(1))) void*)g,
                                     (__attribute__((address_space(3))) void*)l, 16, 0, 0);
}

#define VMCNT(n) asm volatile("s_waitcnt vmcnt(" #n ")" ::: "memory")

// stage one 128x64 bf16 half-tile (row-major, stride ldk) into LDS with T2 swizzle.
__device__ __forceinline__ void stage_half(const u16* __restrict__ g, size_t ldk,
                                           u16* ldsbase, int w, int lane)
{
    #pragma unroll
    for (int cc = 0; cc < 2; cc++) {
        int cb = cc * 512 + w * 64;          // wave-uniform chunk base
        int ci = cb + lane;
        int sc = ci ^ ((ci >> 3) & 7);       // swizzled source chunk (involution)
        gload_lds16(&g[(size_t)(sc >> 3) * ldk + (sc & 7) * 8], ldsbase + cb * 8);
    }
}

// ---------- elementwise f32 -> bf16 ----------
__global__ __launch_bounds__(256)
void cvt_bf16(const float* __restrict__ in, u16* __restrict__ out, int n4)
{
    int i = blockIdx.x * 256 + threadIdx.x;
    if (i >= n4) return;
    float4 v = *(const float4*)&in[(size_t)i * 4];
    u16x4 o; o[0]=f2us(v.x); o[1]=f2us(v.y); o[2]=f2us(v.z); o[3]=f2us(v.w);
    *(u16x4*)&out[(size_t)i * 4] = o;
}

// ---------- out += tmp (f32, vectorized) ----------
__global__ __launch_bounds__(256)
void add_f32(float* __restrict__ out, const float* __restrict__ tmp, int n4)
{
    int i = blockIdx.x * 256 + threadIdx.x;
    if (i >= n4) return;
    float4 a = *(const float4*)&out[(size_t)i * 4];
    float4 b = *(const float4*)&tmp[(size_t)i * 4];
    *(float4*)&out[(size_t)i * 4] = make_float4(a.x+b.x, a.y+b.y, a.z+b.z, a.w+b.w);
}

// ---------- transpose + convert: in f32 [K][N] -> out bf16 [Npad][K], zero-pad n>=N ----------
__global__ __launch_bounds__(256)
void transpose_cvt(const float* __restrict__ in, u16* __restrict__ out, int K, int N)
{
    __shared__ u16 tile[64][65];
    int k0 = blockIdx.x * 64;
    int n0 = blockIdx.y * 64;
    int t = threadIdx.x;
    #pragma unroll
    for (int q = 0; q < 16; q++) {
        int lin = q * 256 + t;
        int r = lin >> 6, c = lin & 63;
        int n = n0 + c;
        float v = (n < N) ? in[(size_t)(k0 + r) * N + n] : 0.f;
        tile[r][c] = f2us(v);
    }
    __syncthreads();
    #pragma unroll
    for (int q = 0; q < 4; q++) {           // 1024 items: r (n-row) x 16 col-groups of 4 k
        int lin = q * 256 + t;
        int r = lin >> 4, cg = lin & 15;
        u16x4 v;
        #pragma unroll
        for (int e = 0; e < 4; e++) v[e] = tile[cg*4 + e][r];
        *(u16x4*)&out[(size_t)(n0 + r) * K + k0 + cg*4] = v;
    }
}

// ---------- 8-phase 256x256 MFMA GEMM (T2-swizzled LDS, plain barriers) ----------
// Stage ledger (round-7 proven): p1: Ah1(t+1); p3: Bh0(t+2); p4: Bh1(t+2)+Ah0(t+2).
// KSPLIT: grid = 2*ntiles; kidx selects K-half; kidx=1 writes Cg2.
template<typename TC, bool KSPLIT>
__global__ __launch_bounds__(512, 1)
void gemm_8ph(const u16* __restrict__ Ag, const u16* __restrict__ Btg,
              TC* __restrict__ Cg, TC* __restrict__ Cg2,
              int M, int N, int Kext, int ldk, int ldc)
{
    __shared__ u16 smA[2][2][8192];   // [dbuf][half][128*64]
    __shared__ u16 smB[2][2][8192];
    const int tid = threadIdx.x;
    const int lane = tid & 63, w = tid >> 6;
    const int wm = w >> 2, wn = w & 3;
    const int lr = lane & 15, kh = lane >> 4;
    const int swz = (lr & 7) << 3;

    int orig = blockIdx.x;
    int ntile = gridDim.x;
    int kidx = 0;
    if constexpr (KSPLIT) { kidx = orig & 1; orig >>= 1; ntile >>= 1; }

    const int nbx = N >> 8;
    const int qq = ntile >> 3, r8 = ntile & 7;
    const int xcd = orig & 7, loc = orig >> 3;
    const int wgid = (xcd < r8 ? xcd*(qq+1) : r8*(qq+1) + (xcd-r8)*qq) + loc;
    const int m0 = (wgid / nbx) * 256;
    const int n0 = (wgid % nbx) * 256;

    if constexpr (KSPLIT) {
        Ag  += (size_t)kidx * Kext;
        Btg += (size_t)kidx * Kext;
        if (kidx) Cg = Cg2;
    }
    const int NT = Kext >> 6;

    f32x4 acc[8][4];
    #pragma unroll
    for (int i = 0; i < 8; i++)
        #pragma unroll
        for (int j = 0; j < 4; j++) acc[i][j] = (f32x4){0.f,0.f,0.f,0.f};

    stage_half(&Ag [(size_t)(m0      ) * ldk      ], ldk, &smA[0][0][0], w, lane);
    stage_half(&Ag [(size_t)(m0 + 128) * ldk      ], ldk, &smA[0][1][0], w, lane);
    stage_half(&Btg[(size_t)(n0      ) * ldk      ], ldk, &smB[0][0][0], w, lane);
    stage_half(&Btg[(size_t)(n0 + 128) * ldk      ], ldk, &smB[0][1][0], w, lane);
    stage_half(&Ag [(size_t)(m0      ) * ldk + 64 ], ldk, &smA[1][0][0], w, lane);
    stage_half(&Btg[(size_t)(n0      ) * ldk + 64 ], ldk, &smB[1][0][0], w, lane);
    stage_half(&Btg[(size_t)(n0 + 128) * ldk + 64 ], ldk, &smB[1][1][0], w, lane);
    VMCNT(6);
    __builtin_amdgcn_s_barrier();

    for (int t = 0; t < NT; ++t) {
        const int d = t & 1;
        const u16* As = &smA[d][wm][0];
        const u16* Bs = &smB[d][wn >> 1][0];
        const int rb = (wn & 1) * 64;

        bf16x8 aF[4][2], bLo[2][2], bHi[2][2];

        // ---- phase 1
        #pragma unroll
        for (int i = 0; i < 4; i++)
            #pragma unroll
            for (int ks = 0; ks < 2; ks++)
                aF[i][ks] = *(const bf16x8*)&As[(i*16 + lr)*64 + ((ks*32 + kh*8) ^ swz)];
        #pragma unroll
        for (int j = 0; j < 2; j++)
            #pragma unroll
            for (int ks = 0; ks < 2; ks++)
                bLo[j][ks] = *(const bf16x8*)&Bs[(rb + j*16 + lr)*64 + ((ks*32 + kh*8) ^ swz)];
        if (t + 1 < NT)
            stage_half(&Ag[(size_t)(m0 + 128) * ldk + (t+1)*64], ldk, &smA[d^1][1][0], w, lane);
        __builtin_amdgcn_s_barrier();
        __builtin_amdgcn_s_setprio(1);
        #pragma unroll
        for (int i = 0; i < 4; i++)
            #pragma unroll
            for (int j = 0; j < 2; j++)
                #pragma unroll
                for (int ks = 0; ks < 2; ks++)
                    acc[i][j] = __builtin_amdgcn_mfma_f32_16x16x32_bf16(aF[i][ks], bLo[j][ks], acc[i][j], 0, 0, 0);
        __builtin_amdgcn_s_setprio(0);
        __builtin_amdgcn_s_barrier();

        // ---- phase 2
        #pragma unroll
        for (int j = 0; j < 2; j++)
            #pragma unroll
            for (int ks = 0; ks < 2; ks++)
                bHi[j][ks] = *(const bf16x8*)&Bs[(rb + (2+j)*16 + lr)*64 + ((ks*32 + kh*8) ^ swz)];
        __builtin_amdgcn_s_barrier();
        __builtin_amdgcn_s_setprio(1);
        #pragma unroll
        for (int i = 0; i < 4; i++)
            #pragma unroll
            for (int j = 0; j < 2; j++)
                #pragma unroll
                for (int ks = 0; ks < 2; ks++)
                    acc[i][2+j] = __builtin_amdgcn_mfma_f32_16x16x32_bf16(aF[i][ks], bHi[j][ks], acc[i][2+j], 0, 0, 0);
        __builtin_amdgcn_s_setprio(0);
        __builtin_amdgcn_s_barrier();

        // ---- phase 3
        #pragma unroll
        for (int i = 0; i < 4; i++)
            #pragma unroll
            for (int ks = 0; ks < 2; ks++)
                aF[i][ks] = *(const bf16x8*)&As[(64 + i*16 + lr)*64 + ((ks*32 + kh*8) ^ swz)];
        if (t + 2 < NT)
            stage_half(&Btg[(size_t)(n0) * ldk + (t+2)*64], ldk, &smB[d][0][0], w, lane);
        __builtin_amdgcn_s_barrier();
        __builtin_amdgcn_s_setprio(1);
        #pragma unroll
        for (int i = 0; i < 4; i++)
            #pragma unroll
            for (int j = 0; j < 2; j++)
                #pragma unroll
                for (int ks = 0; ks < 2; ks++)
                    acc[4+i][j] = __builtin_amdgcn_mfma_f32_16x16x32_bf16(aF[i][ks], bLo[j][ks], acc[4+i][j], 0, 0, 0);
        __builtin_amdgcn_s_setprio(0);
        __builtin_amdgcn_s_barrier();

        // ---- phase 4
        if (t + 2 < NT) {
            stage_half(&Btg[(size_t)(n0 + 128) * ldk + (t+2)*64], ldk, &smB[d][1][0], w, lane);
            stage_half(&Ag [(size_t)(m0      ) * ldk + (t+2)*64], ldk, &smA[d][0][0], w, lane);
        }
        __builtin_amdgcn_s_barrier();
        __builtin_amdgcn_s_setprio(1);
        #pragma unroll
        for (int i = 0; i < 4; i++)
            #pragma unroll
            for (int j = 0; j < 2; j++)
                #pragma unroll
                for (int ks = 0; ks < 2; ks++)
                    acc[4+i][2+j] = __builtin_amdgcn_mfma_f32_16x16x32_bf16(aF[i][ks], bHi[j][ks], acc[4+i][2+j], 0, 0, 0);
        __builtin_amdgcn_s_setprio(0);
        if (t < NT - 2)       { VMCNT(6); }
        else if (t == NT - 2) { VMCNT(0); }
        __builtin_amdgcn_s_barrier();
    }

    #pragma unroll
    for (int mf = 0; mf < 8; mf++) {
        #pragma unroll
        for (int nf = 0; nf < 4; nf++) {
            int r = m0 + wm*128 + mf*16 + kh*4;
            int cidx = n0 + wn*64 + nf*16 + lr;
            #pragma unroll
            for (int q = 0; q < 4; q++) {
                if constexpr (sizeof(TC) == 4) Cg[(size_t)(r+q)*ldc + cidx] = acc[mf][nf][q];
                else                           Cg[(size_t)(r+q)*ldc + cidx] = f2us(acc[mf][nf][q]);
            }
        }
    }
}

// ---------- 2-phase 128x128 MFMA GEMM — used for GEMM1's N-tail ----------
template<typename TC>
__global__ __launch_bounds__(256)
void gemm_mfma(const u16* __restrict__ A, const u16* __restrict__ Bt,
               TC* __restrict__ C, int M, int N, int K, int ldc)
{
    __shared__ u16 Asm[128][32];
    __shared__ u16 Bsm[128][32];
    const int t = threadIdx.x;
    const int lane = t & 63, w = t >> 6;
    const int wr = w >> 1, wc = w & 1;
    const int lr = lane & 15, kh = lane >> 4;

    const int nwg = gridDim.x * gridDim.y;
    const int orig = blockIdx.y * gridDim.x + blockIdx.x;
    const int qq = nwg >> 3, r8 = nwg & 7;
    const int xcd = orig & 7, loc = orig >> 3;
    const int wgid = (xcd < r8 ? xcd*(qq+1) : r8*(qq+1) + (xcd-r8)*qq) + loc;
    const int m0 = (wgid / gridDim.x) * 128;
    const int n0 = (wgid % gridDim.x) * 128;

    f32x4 acc[4][4];
    #pragma unroll
    for (int i = 0; i < 4; i++)
        #pragma unroll
        for (int j = 0; j < 4; j++) acc[i][j] = (f32x4){0.f,0.f,0.f,0.f};

    for (int k0 = 0; k0 < K; k0 += 32) {
        #pragma unroll
        for (int i = 0; i < 2; i++) {
            int cb = i * 256 + w * 64;
            int chunk = cb + lane;
            int row = chunk >> 2, kb = chunk & 3;
            gload_lds16(&A[(size_t)(m0 + row) * K + k0 + kb * 8], &Asm[0][0] + cb * 8);
            gload_lds16(&Bt[(size_t)(n0 + row) * K + k0 + kb * 8], &Bsm[0][0] + cb * 8);
        }
        __syncthreads();
        bf16x8 af[4], bf[4];
        #pragma unroll
        for (int i = 0; i < 4; i++)
            af[i] = *(const bf16x8*)&Asm[wr*64 + i*16 + lr][kh*8];
        #pragma unroll
        for (int j = 0; j < 4; j++)
            bf[j] = *(const bf16x8*)&Bsm[wc*64 + j*16 + lr][kh*8];
        #pragma unroll
        for (int i = 0; i < 4; i++)
            #pragma unroll
            for (int j = 0; j < 4; j++)
                acc[i][j] = __builtin_amdgcn_mfma_f32_16x16x32_bf16(af[i], bf[j], acc[i][j], 0, 0, 0);
        __syncthreads();
    }
    #pragma unroll
    for (int i = 0; i < 4; i++) {
        #pragma unroll
        for (int j = 0; j < 4; j++) {
            int r = m0 + wr*64 + i*16 + kh*4;
            int cidx = n0 + wc*64 + j*16 + lr;
            #pragma unroll
            for (int q = 0; q < 4; q++) {
                if constexpr (sizeof(TC) == 4) C[(size_t)(r+q)*ldc + cidx] = acc[i][j][q];
                else                           C[(size_t)(r+q)*ldc + cidx] = f2us(acc[i][j][q]);
            }
        }
    }
}

// ---------------- conv1d (K=4) + bias + SiLU, 8 channels/thread ----------------
__global__ __launch_bounds__(256)
void conv_silu(const u16* __restrict__ zx, const float* __restrict__ cw,
               const float* __restrict__ cb, u16* __restrict__ xconv,
               u16* __restrict__ Bbuf, u16* __restrict__ Cbuf)
{
    int idx = blockIdx.x * 256 + threadIdx.x;
    int cg = idx % (CONV_DIM / 8);
    int r  = idx / (CONV_DIM / 8);
    int c0 = cg * 8;
    int l  = r & (SEQ - 1);

    float y[8];
    {
        float4 b0 = *(const float4*)&cb[c0];
        float4 b1 = *(const float4*)&cb[c0 + 4];
        y[0]=b0.x; y[1]=b0.y; y[2]=b0.z; y[3]=b0.w;
        y[4]=b1.x; y[5]=b1.y; y[6]=b1.z; y[7]=b1.w;
    }
    float cwf[8][4];
    #pragma unroll
    for (int e = 0; e < 8; e++) {
        float4 v = *(const float4*)&cw[(c0 + e) * 4];
        cwf[e][0]=v.x; cwf[e][1]=v.y; cwf[e][2]=v.z; cwf[e][3]=v.w;
    }
    #pragma unroll
    for (int k = 0; k < 4; k++) {
        if (l + k - 3 >= 0) {
            u16x8 v = *(const u16x8*)&zx[(size_t)(r + k - 3) * LD_ZX + D_INNER + c0];
            #pragma unroll
            for (int e = 0; e < 8; e++) y[e] += us2f(v[e]) * cwf[e][k];
        }
    }
    u16x8 o;
    #pragma unroll
    for (int e = 0; e < 8; e++) {
        float s = y[e] / (1.f + expf(-y[e]));
        o[e] = f2us(s);
    }
    if (c0 < D_INNER)                *(u16x8*)&xconv[(size_t)r * D_INNER + c0] = o;
    else if (c0 < D_INNER + D_STATE) *(u16x8*)&Bbuf[(size_t)r * D_STATE + (c0 - D_INNER)] = o;
    else                             *(u16x8*)&Cbuf[(size_t)r * D_STATE + (c0 - D_INNER - D_STATE)] = o;
}

// ---------------- dt softplus + per-chunk cumsum ----------------
__global__ __launch_bounds__(256)
void dt_acs(const u16* __restrict__ zx, const float* __restrict__ Aparam,
            const float* __restrict__ dt_bias, float* __restrict__ dtT,
            float* __restrict__ Acs)
{
    __shared__ float sb[CHUNK];
    int blk = blockIdx.x;
    int c = blk & 7, h = (blk >> 3) & 63, b = blk >> 9;
    int t = threadIdx.x;
    int lg = c * CHUNK + t;
    int row = b * SEQ + lg;
    float x = us2f(zx[(size_t)row * LD_ZX + DT_OFF + h]) + dt_bias[h];
    float dt = (x > 20.f) ? x : log1pf(expf(x));
    float v = dt * Aparam[h];
    sb[t] = v; __syncthreads();
    #pragma unroll
    for (int off = 1; off < 256; off <<= 1) {
        float add = (t >= off) ? sb[t - off] : 0.f;
        __syncthreads();
        v += add; sb[t] = v;
        __syncthreads();
    }
    int o = (b * NHEADS + h) * SEQ + lg;
    dtT[o] = dt;
    Acs[o] = v;
}

// ---------------- per-chunk states via MFMA ----------------
__global__ __launch_bounds__(256)
void chunk_states_mfma(const u16* __restrict__ xconv, const u16* __restrict__ Bbuf,
                       const float* __restrict__ dtT, const float* __restrict__ Acs,
                       float* __restrict__ states)
{
    __shared__ u16 Btsh[128][72];
    __shared__ u16 xtsh[64][72];
    __shared__ float acs_sh[CHUNK];
    __shared__ float dt_sh[CHUNK];

    const int blk = blockIdx.x;
    const int h = blk & 63, c = (blk >> 6) & 7, b = blk >> 9;
    const int t = threadIdx.x;
    const int lane = t & 63, w = t >> 6;
    const int wr = w >> 1, wc = w & 1;
    const int lr = lane & 15, kh = lane >> 4;
    const int bh = b * NHEADS + h;
    const size_t rowbase = (size_t)(b * SEQ + c * CHUNK);

    acs_sh[t] = Acs[(size_t)bh * SEQ + c * CHUNK + t];
    dt_sh[t]  = dtT[(size_t)bh * SEQ + c * CHUNK + t];
    __syncthreads();
    const float acs_last = acs_sh[CHUNK - 1];

    f32x4 acc[2][4];
    #pragma unroll
    for (int i = 0; i < 2; i++)
        #pragma unroll
        for (int j = 0; j < 4; j++) acc[i][j] = (f32x4){0.f,0.f,0.f,0.f};

    for (int lt = 0; lt < 4; lt++) {
        __syncthreads();
        const int s = t & 63;
        const int sg = lt * 64 + s;
        const float wgt = dt_sh[sg] * expf(acs_last - acs_sh[sg]);
        {
            int ng = (t >> 6) * 32;
            const u16* src = &Bbuf[(rowbase + sg) * D_STATE + ng];
            #pragma unroll
            for (int q = 0; q < 4; q++) {
                u16x8 v = *(const u16x8*)&src[q * 8];
                #pragma unroll
                for (int e = 0; e < 8; e++)
                    Btsh[ng + q*8 + e][s] = f2us(us2f(v[e]) * wgt);
            }
        }
        {
            int pg = (t >> 6) * 16;
            const u16* src = &xconv[(rowbase + sg) * D_INNER + h * HEAD_DIM + pg];
            u16x8 v0 = *(const u16x8*)&src[0];
            u16x8 v1 = *(const u16x8*)&src[8];
            #pragma unroll
            for (int e = 0; e < 8; e++) { xtsh[pg + e][s] = v0[e]; xtsh[pg + 8 + e][s] = v1[e]; }
        }
        __syncthreads();
        #pragma unroll
        for (int kk = 0; kk < 2; kk++) {
            bf16x8 af[2], bf[4];
            #pragma unroll
            for (int i = 0; i < 2; i++)
                af[i] = *(const bf16x8*)&xtsh[wr*32 + i*16 + lr][kk*32 + kh*8];
            #pragma unroll
            for (int j = 0; j < 4; j++)
                bf[j] = *(const bf16x8*)&Btsh[wc*64 + j*16 + lr][kk*32 + kh*8];
            #pragma unroll
            for (int i = 0; i < 2; i++)
                #pragma unroll
                for (int j = 0; j < 4; j++)
                    acc[i][j] = __builtin_amdgcn_mfma_f32_16x16x32_bf16(af[i], bf[j], acc[i][j], 0, 0, 0);
        }
    }
    size_t base = ((size_t)((b*NCHUNK + c)*NHEADS + h)) * (HEAD_DIM * D_STATE);
    #pragma unroll
    for (int i = 0; i < 2; i++) {
        #pragma unroll
        for (int j = 0; j < 4; j++) {
            int p = wr*32 + i*16 + kh*4;
            int n = wc*64 + j*16 + lr;
            #pragma unroll
            for (int q = 0; q < 4; q++)
                states[base + (size_t)(p + q) * D_STATE + n] = acc[i][j][q];
        }
    }
}

// ---------------- inter-chunk recurrence ----------------
__global__ __launch_bounds__(256)
void state_recurrence(float* __restrict__ states, const float* __restrict__ Acs)
{
    int idx = blockIdx.x * 256 + threadIdx.x;
    int pn = idx & 8191;
    int bh = idx >> 13;
    int b = bh >> 6, h = bh & 63;
    float E = 0.f;
    for (int c = 0; c < NCHUNK; c++) {
        size_t off = ((size_t)((b*NCHUNK + c)*NHEADS + h)) * 8192 + pn;
        float s = states[off];
        states[off] = E;
        float cs = Acs[(size_t)(b*NHEADS + h) * SEQ + c*CHUNK + 255];
        E = expf(cs) * E + s;
    }
}

// ---------------- chunk output, MFMA, swapped-operand version ----------------
// S^T = mfma(B-frag, C-frag): lane holds S^T[s=js*16+kh*4+q][l=i*16+lr] -> 4 consecutive s
// => u16x4 P stores into Pt[l][s]. PV/Y_off swapped: yacc[j][i] = Y[l=i*16+lr][p=j*16+kh*4+q]
// => u16x4 epilogue with fused D-skip. Wave w skips s-tiles st>w (fully masked).
__global__ __launch_bounds__(256, 1)
void chunk_output_mfma(const u16* __restrict__ xconv, const u16* __restrict__ Bbuf,
                       const u16* __restrict__ Cbuf, const float* __restrict__ dtT,
                       const float* __restrict__ Acs, const float* __restrict__ states,
                       const float* __restrict__ Dparam, u16* __restrict__ Y)
{
    __shared__ u16 Bsm[64][130];       // B tile [s][n]; later prev [p][n]
    __shared__ u16 xt[64][72];         // x^T tile [p][s] (72: 16B-aligned rows)
    __shared__ u16 Pt[4][64][72];      // per-wave P [l][s]
    __shared__ float acs_sh[CHUNK];
    __shared__ float dt_sh[CHUNK];

    const int blk = blockIdx.x;                 // b*512 + c*64 + h
    const int h = blk & 63, c = (blk >> 6) & 7, b = blk >> 9;
    const int t = threadIdx.x;
    const int lane = t & 63, w = t >> 6;
    const int lr = lane & 15, kh = lane >> 4;
    const int bh = b * NHEADS + h;
    const size_t rowbase = (size_t)(b * SEQ + c * CHUNK);

    acs_sh[t] = Acs[(size_t)bh * SEQ + c * CHUNK + t];
    dt_sh[t]  = dtT[(size_t)bh * SEQ + c * CHUNK + t];

    // C fragments: af[i][kk][e] = C[w*64+i*16+lr][kk*32+kh*8+e]
    bf16x8 af[4][4];
    #pragma unroll
    for (int i = 0; i < 4; i++)
        #pragma unroll
        for (int kk = 0; kk < 4; kk++)
            af[i][kk] = *(const bf16x8*)&Cbuf[(rowbase + w*64 + i*16 + lr) * D_STATE + kk*32 + kh*8];

    __syncthreads();                    // acs_sh/dt_sh visible
    float acs_l[4];
    #pragma unroll
    for (int i = 0; i < 4; i++) acs_l[i] = acs_sh[w*64 + i*16 + lr];

    f32x4 yacc[4][4];                   // [j=p-block][i=l-block]
    #pragma unroll
    for (int j = 0; j < 4; j++)
        #pragma unroll
        for (int i = 0; i < 4; i++) yacc[j][i] = (f32x4){0.f,0.f,0.f,0.f};

    for (int st = 0; st < 4; st++) {
        __syncthreads();
        {   // stage B tile [s][n]
            int sr = t >> 2, cg = (t & 3) * 32;
            const u16* src = &Bbuf[(rowbase + st*64 + sr) * D_STATE + cg];
            #pragma unroll
            for (int q = 0; q < 4; q++)
                *(u16x8*)&Bsm[sr][cg + q*8] = *(const u16x8*)&src[q*8];
        }
        {   // stage x^T tile [p][s]
            int s = t & 63, pg = t >> 6;
            const u16* src = &xconv[(rowbase + st*64 + s) * D_INNER + h*HEAD_DIM + pg*16];
            u16x8 v0 = *(const u16x8*)&src[0];
            u16x8 v1 = *(const u16x8*)&src[8];
            #pragma unroll
            for (int q = 0; q < 8; q++) { xt[pg*16 + q][s] = v0[q]; xt[pg*16 + 8 + q][s] = v1[q]; }
        }
        __syncthreads();
        if (st > w) continue;           // fully-masked tile; wave-uniform; no barrier inside

        // S^T[s][l] = B . C^T  (A = B-frag rows s, Bop = af)
        f32x4 sacc[4][4];               // [js = s-block][i = l-block]
        #pragma unroll
        for (int js = 0; js < 4; js++)
            #pragma unroll
            for (int i = 0; i < 4; i++) sacc[js][i] = (f32x4){0.f,0.f,0.f,0.f};
        #pragma unroll
        for (int kk = 0; kk < 4; kk++) {
            bf16x8 bA[4];
            #pragma unroll
            for (int js = 0; js < 4; js++)
                bA[js] = *(const bf16x8*)&Bsm[js*16 + lr][kk*32 + kh*8];
            #pragma unroll
            for (int js = 0; js < 4; js++)
                #pragma unroll
                for (int i = 0; i < 4; i++)
                    sacc[js][i] = __builtin_amdgcn_mfma_f32_16x16x32_bf16(bA[js], af[i][kk], sacc[js][i], 0, 0, 0);
        }
        // mask + scale + vectorized P store: lane holds 4 consecutive s at fixed l
        #pragma unroll
        for (int js = 0; js < 4; js++) {
            int sg0 = st*64 + js*16 + kh*4;
            float as[4], ds[4];
            #pragma unroll
            for (int q = 0; q < 4; q++) { as[q] = acs_sh[sg0 + q]; ds[q] = dt_sh[sg0 + q]; }
            #pragma unroll
            for (int i = 0; i < 4; i++) {
                int lg = w*64 + i*16 + lr;
                u16x4 pv;
                #pragma unroll
                for (int q = 0; q < 4; q++) {
                    float fac = (sg0 + q <= lg) ? expf(fminf(acs_l[i] - as[q], 0.f)) * ds[q] : 0.f;
                    pv[q] = f2us(sacc[js][i][q] * fac);
                }
                *(u16x4*)&Pt[w][i*16 + lr][js*16 + kh*4] = pv;
            }
        }
        // PV swapped: Y^T[p][l] += x^T[p][s] . P[l][s]  (A = x^T frag, Bop = P frag)
        #pragma unroll
        for (int kk2 = 0; kk2 < 2; kk2++) {
            bf16x8 xA[4], pB[4];
            #pragma unroll
            for (int j = 0; j < 4; j++)
                xA[j] = *(const bf16x8*)&xt[j*16 + lr][kk2*32 + kh*8];
            #pragma unroll
            for (int i = 0; i < 4; i++)
                pB[i] = *(const bf16x8*)&Pt[w][i*16 + lr][kk2*32 + kh*8];
            #pragma unroll
            for (int j = 0; j < 4; j++)
                #pragma unroll
                for (int i = 0; i < 4; i++)
                    yacc[j][i] = __builtin_amdgcn_mfma_f32_16x16x32_bf16(xA[j], pB[i], yacc[j][i], 0, 0, 0);
        }
    }

    // Y_off swapped: Y^T[p][l] += prev[p][n] . (el * C[l][n])
    __syncthreads();
    {   // stage prev (f32 -> bf16) into Bsm [p][n]
        int p = t >> 2, ng = (t & 3) * 32;
        const float* src = &states[((size_t)((b*NCHUNK + c)*NHEADS + h)) * 8192 + (size_t)p * 128 + ng];
        #pragma unroll
        for (int q = 0; q < 4; q++) {
            float4 v0 = *(const float4*)&src[q*8];
            float4 v1 = *(const float4*)&src[q*8 + 4];
            u16x8 o;
            o[0]=f2us(v0.x); o[1]=f2us(v0.y); o[2]=f2us(v0.z); o[3]=f2us(v0.w);
            o[4]=f2us(v1.x); o[5]=f2us(v1.y); o[6]=f2us(v1.z); o[7]=f2us(v1.w);
            *(u16x8*)&Bsm[p][ng + q*8] = o;
        }
    }
    __syncthreads();
    {
        float el[4];
        #pragma unroll
        for (int i = 0; i < 4; i++) el[i] = expf(acs_l[i]);
        #pragma unroll
        for (int kk = 0; kk < 4; kk++) {
            bf16x8 pvA[4];
            #pragma unroll
            for (int j = 0; j < 4; j++)
                pvA[j] = *(const bf16x8*)&Bsm[j*16 + lr][kk*32 + kh*8];
            #pragma unroll
            for (int i = 0; i < 4; i++) {
                bf16x8 ae;
                #pragma unroll
                for (int e = 0; e < 8; e++)
                    ae[e] = (short)f2us(us2f((u16)af[i][kk][e]) * el[i]);
                #pragma unroll
                for (int j = 0; j < 4; j++)
                    yacc[j][i] = __builtin_amdgcn_mfma_f32_16x16x32_bf16(pvA[j], ae, yacc[j][i], 0, 0, 0);
            }
        }
    }

    // epilogue: lane holds Y[l = w*64+i*16+lr][p = j*16+kh*4+q] -> u16x4 stores, fused D-skip
    float Dh = Dparam[h];
    #pragma unroll
    for (int i = 0; i < 4; i++) {
        #pragma unroll
        for (int j = 0; j < 4; j++) {
            size_t o = (rowbase + w*64 + i*16 + lr) * D_INNER + h*HEAD_DIM + j*16 + kh*4;
            u16x4 xv = *(const u16x4*)&xconv[o];
            u16x4 ov;
            #pragma unroll
            for (int q = 0; q < 4; q++)
                ov[q] = f2us(yacc[j][i][q] + Dh * us2f(xv[q]));
            *(u16x4*)&Y[o] = ov;
        }
    }
}

// ---------------- gated RMSNorm ----------------
__global__ __launch_bounds__(256)
void gated_rmsnorm_k(u16* __restrict__ Y, const u16* __restrict__ zx,
                     const float* __restrict__ nw)
{
    __shared__ float xs[D_INNER];
    __shared__ float red[8];
    int row = blockIdx.x;
    int t = threadIdx.x;
    float ss = 0.f;
    for (int i = t*8; i < D_INNER; i += 2048) {
        u16x8 yv = *(const u16x8*)&Y[(size_t)row * D_INNER + i];
        u16x8 zv = *(const u16x8*)&zx[(size_t)row * LD_ZX + i];
        #pragma unroll
        for (int q = 0; q < 8; q++) {
            float x = us2f(yv[q]) * siluf(us2f(zv[q]));
            xs[i + q] = x;
            ss += x * x;
        }
    }
    #pragma unroll
    for (int off = 32; off > 0; off >>= 1) ss += __shfl_down(ss, off);
    int wid = t >> 6, lane = t & 63;
    if (lane == 0) red[wid] = ss;
    __syncthreads();
    if (t == 0) {
        float tot = red[0] + red[1] + red[2] + red[3];
        red[0] = rsqrtf(tot / (float)D_INNER + EPS_RMS);
    }
    __syncthreads();
    float sc = red[0];
    for (int i = t*8; i < D_INNER; i += 2048) {
        u16x8 o;
        #pragma unroll
        for (int q = 0; q < 8; q++) o[q] = f2us(xs[i + q] * sc * nw[i + q]);
        *(u16x8*)&Y[(size_t)row * D_INNER + i] = o;
    }
}

__global__ void ws_fail_k(float* out, float mb){ out[threadIdx.x] = mb; }

// ---------------- launch ----------------
extern "C" void kernel_launch(void* const* d_in, const int* in_sizes, int n_in,
                              void* d_out, int out_size, void* d_ws, size_t ws_size,
                              hipStream_t stream)
{
    const float* hidden  = (const float*)d_in[0];
    const float* W_in    = (const float*)d_in[1];
    const float* conv_w  = (const float*)d_in[2];
    const float* conv_b  = (const float*)d_in[3];
    const float* Aparam  = (const float*)d_in[4];
    const float* Dparam  = (const float*)d_in[5];
    const float* dt_bias = (const float*)d_in[6];
    const float* norm_w  = (const float*)d_in[7];
    const float* W_out   = (const float*)d_in[8];
    float* out = (float*)d_out;

    const int M = BATCH * SEQ;  // 4096

    size_t off = 0;
    char* wsb = (char*)d_ws;
    u16*   zx     = (u16*)  (wsb + off); off += (size_t)M * LD_ZX * 2;
    u16*   xconv  = (u16*)  (wsb + off); off += (size_t)M * D_INNER * 2;
    u16*   Bbuf   = (u16*)  (wsb + off); off += (size_t)M * D_STATE * 2;
    u16*   Cbuf   = (u16*)  (wsb + off); off += (size_t)M * D_STATE * 2;
    float* dtT    = (float*)(wsb + off); off += (size_t)BATCH * NHEADS * SEQ * 4;
    float* Acs    = (float*)(wsb + off); off += (size_t)BATCH * NHEADS * SEQ * 4;
    float* states = (float*)(wsb + off); off += (size_t)BATCH * NCHUNK * NHEADS * HEAD_DIM * D_STATE * 4;
    u16*   Ybuf   = (u16*)  (wsb + off); off += (size_t)M * D_INNER * 2;
    u16*   hbf    = (u16*)  (wsb + off); off += (size_t)M * D_MODEL * 2;
    u16*   WtIn   = (u16*)  (wsb + off); off += (size_t)LD_ZX * D_MODEL * 2;
    u16*   WtOut  = (u16*)  (wsb + off); off += (size_t)D_MODEL * D_INNER * 2;
    float* tmpf   = (float*)zx;          // aliases zx (dead after gated_rmsnorm)

    if (off > ws_size) {
        ws_fail_k<<<1, 64, 0, stream>>>(out, (float)(ws_size >> 20));
        return;
    }

    cvt_bf16<<<(M * D_MODEL / 4 + 255) / 256, 256, 0, stream>>>(hidden, hbf, M * D_MODEL / 4);
    transpose_cvt<<<dim3(D_MODEL/64, LD_ZX/64), 256, 0, stream>>>(W_in, WtIn, D_MODEL, D_IN_PROJ);
    transpose_cvt<<<dim3(D_INNER/64, D_MODEL/64), 256, 0, stream>>>(W_out, WtOut, D_INNER, D_MODEL);

    // GEMM1 main: zx[:, 0:8192] — 512 blocks = exactly 2 CU-rounds
    gemm_8ph<u16, false><<<(8192/256) * (M/256), 512, 0, stream>>>(
        hbf, WtIn, zx, nullptr, M, 8192, D_MODEL, D_MODEL, LD_ZX);
    // GEMM1 tail: zx[:, 8192:8704]
    gemm_mfma<u16><<<dim3(4, M/128), 256, 0, stream>>>(
        hbf, WtIn + (size_t)8192 * D_MODEL, zx + 8192, M, 512, D_MODEL, LD_ZX);

    conv_silu<<<(M * CONV_DIM / 8) / 256, 256, 0, stream>>>(zx, conv_w, conv_b, xconv, Bbuf, Cbuf);
    dt_acs<<<BATCH * NHEADS * NCHUNK, 256, 0, stream>>>(zx, Aparam, dt_bias, dtT, Acs);
    chunk_states_mfma<<<BATCH * NCHUNK * NHEADS, 256, 0, stream>>>(xconv, Bbuf, dtT, Acs, states);
    state_recurrence<<<(BATCH * NHEADS * HEAD_DIM * D_STATE) / 256, 256, 0, stream>>>(states, Acs);
    chunk_output_mfma<<<BATCH * NCHUNK * NHEADS, 256, 0, stream>>>(xconv, Bbuf, Cbuf, dtT, Acs, states, Dparam, Ybuf);
    gated_rmsnorm_k<<<M, 256, 0, stream>>>(Ybuf, zx, norm_w);   // last reader of zx

    // GEMM2 K-split-2: 256 blocks = exactly 1 CU-round; then out += tmpf
    gemm_8ph<float, true><<<2 * (D_MODEL/256) * (M/256), 512, 0, stream>>>(
        Ybuf, WtOut, out, tmpf, M, D_MODEL, D_INNER/2, D_INNER, D_MODEL);
    add_f32<<<(M * D_MODEL / 4 + 255) / 256, 256, 0, stream>>>(out, tmpf, M * D_MODEL / 4);
}

// Round 12
// 538.412 us; speedup vs baseline: 1.1120x; 1.0511x over previous
//
#include <hip/hip_runtime.h>
#include <hip/hip_bf16.h>
#include <math.h>

#define D_MODEL   2048
#define D_INNER   4096
#define NHEADS    64
#define HEAD_DIM  64
#define D_STATE   128
#define CHUNK     256
#define CONV_DIM  (D_INNER + 2*D_STATE)            // 4352
#define D_IN_PROJ (2*D_INNER + 2*D_STATE + NHEADS) // 8512
#define LD_ZX     8704                             // D_IN_PROJ padded to 256
#define DT_OFF    (2*D_INNER + 2*D_STATE)          // 8448
#define BATCH     2
#define SEQ       2048
#define NCHUNK    (SEQ/CHUNK)                      // 8
#define EPS_RMS   1e-5f

typedef unsigned short u16;
typedef __attribute__((ext_vector_type(8))) unsigned short u16x8;
typedef __attribute__((ext_vector_type(4))) unsigned short u16x4;
typedef __attribute__((ext_vector_type(8))) short bf16x8;   // MFMA A/B frag (8 bf16)
typedef __attribute__((ext_vector_type(4))) float f32x4;    // MFMA C/D frag

__device__ __forceinline__ float us2f(u16 u){
    union { unsigned int i; float f; } c; c.i = ((unsigned int)u) << 16; return c.f;
}
__device__ __forceinline__ u16 f2us(float f){
    union { float f; unsigned int i; } c; c.f = f;
    unsigned int r = c.i + 0x7FFFu + ((c.i >> 16) & 1u);
    return (u16)(r >> 16);
}
__device__ __forceinline__ float siluf(float x){ return x / (1.f + expf(-x)); }

__device__ __forceinline__ void gload_lds16(const void* g, void* l) {
    __builtin_amdgcn_global_load_lds((const __attribute__((address_space(1))) void*)g,
                                     (__attribute__((address_space(3))) void*)l, 16, 0, 0);
}

#define VMCNT(n) asm volatile("s_waitcnt vmcnt(" #n ")" ::: "memory")

// stage one 128x64 bf16 half-tile (row-major, stride ldk) into LDS with T2 swizzle.
__device__ __forceinline__ void stage_half(const u16* __restrict__ g, size_t ldk,
                                           u16* ldsbase, int w, int lane)
{
    #pragma unroll
    for (int cc = 0; cc < 2; cc++) {
        int cb = cc * 512 + w * 64;          // wave-uniform chunk base
        int ci = cb + lane;
        int sc = ci ^ ((ci >> 3) & 7);       // swizzled source chunk (involution)
        gload_lds16(&g[(size_t)(sc >> 3) * ldk + (sc & 7) * 8], ldsbase + cb * 8);
    }
}

// ---------- elementwise f32 -> bf16 ----------
__global__ __launch_bounds__(256)
void cvt_bf16(const float* __restrict__ in, u16* __restrict__ out, int n4)
{
    int i = blockIdx.x * 256 + threadIdx.x;
    if (i >= n4) return;
    float4 v = *(const float4*)&in[(size_t)i * 4];
    u16x4 o; o[0]=f2us(v.x); o[1]=f2us(v.y); o[2]=f2us(v.z); o[3]=f2us(v.w);
    *(u16x4*)&out[(size_t)i * 4] = o;
}

// ---------- out += tmp (f32, vectorized) ----------
__global__ __launch_bounds__(256)
void add_f32(float* __restrict__ out, const float* __restrict__ tmp, int n4)
{
    int i = blockIdx.x * 256 + threadIdx.x;
    if (i >= n4) return;
    float4 a = *(const float4*)&out[(size_t)i * 4];
    float4 b = *(const float4*)&tmp[(size_t)i * 4];
    *(float4*)&out[(size_t)i * 4] = make_float4(a.x+b.x, a.y+b.y, a.z+b.z, a.w+b.w);
}

// ---------- sum 4 f32 partials [M][512] -> bf16 into zx cols [8192:8704] ----------
__global__ __launch_bounds__(256)
void add4_cvt_tail(const float* __restrict__ tp, u16* __restrict__ zx, int M)
{
    int idx = blockIdx.x * 256 + threadIdx.x;    // < M*512/8
    int r = idx >> 6, c8 = idx & 63;
    const size_t stride = (size_t)M * 512;
    const float* p = &tp[(size_t)r * 512 + c8 * 8];
    u16x8 o;
    #pragma unroll
    for (int e = 0; e < 8; e++) {
        float s = p[e] + p[stride + e] + p[2*stride + e] + p[3*stride + e];
        o[e] = f2us(s);
    }
    *(u16x8*)&zx[(size_t)r * LD_ZX + 8192 + c8 * 8] = o;
}

// ---------- transpose + convert: in f32 [K][N] -> out bf16 [Npad][K], zero-pad n>=N ----------
__global__ __launch_bounds__(256)
void transpose_cvt(const float* __restrict__ in, u16* __restrict__ out, int K, int N)
{
    __shared__ u16 tile[64][65];
    int k0 = blockIdx.x * 64;
    int n0 = blockIdx.y * 64;
    int t = threadIdx.x;
    #pragma unroll
    for (int q = 0; q < 16; q++) {
        int lin = q * 256 + t;
        int r = lin >> 6, c = lin & 63;
        int n = n0 + c;
        float v = (n < N) ? in[(size_t)(k0 + r) * N + n] : 0.f;
        tile[r][c] = f2us(v);
    }
    __syncthreads();
    #pragma unroll
    for (int q = 0; q < 4; q++) {
        int lin = q * 256 + t;
        int r = lin >> 4, cg = lin & 15;
        u16x4 v;
        #pragma unroll
        for (int e = 0; e < 4; e++) v[e] = tile[cg*4 + e][r];
        *(u16x4*)&out[(size_t)(n0 + r) * K + k0 + cg*4] = v;
    }
}

// ---------- 8-phase 256x256 MFMA GEMM (T2-swizzled LDS, plain barriers) ----------
// Stage ledger (round-7 proven): p1: Ah1(t+1); p3: Bh0(t+2); p4: Bh1(t+2)+Ah0(t+2).
template<typename TC, bool KSPLIT>
__global__ __launch_bounds__(512, 1)
void gemm_8ph(const u16* __restrict__ Ag, const u16* __restrict__ Btg,
              TC* __restrict__ Cg, TC* __restrict__ Cg2,
              int M, int N, int Kext, int ldk, int ldc)
{
    __shared__ u16 smA[2][2][8192];   // [dbuf][half][128*64]
    __shared__ u16 smB[2][2][8192];
    const int tid = threadIdx.x;
    const int lane = tid & 63, w = tid >> 6;
    const int wm = w >> 2, wn = w & 3;
    const int lr = lane & 15, kh = lane >> 4;
    const int swz = (lr & 7) << 3;

    int orig = blockIdx.x;
    int ntile = gridDim.x;
    int kidx = 0;
    if constexpr (KSPLIT) { kidx = orig & 1; orig >>= 1; ntile >>= 1; }

    const int nbx = N >> 8;
    const int qq = ntile >> 3, r8 = ntile & 7;
    const int xcd = orig & 7, loc = orig >> 3;
    const int wgid = (xcd < r8 ? xcd*(qq+1) : r8*(qq+1) + (xcd-r8)*qq) + loc;
    const int m0 = (wgid / nbx) * 256;
    const int n0 = (wgid % nbx) * 256;

    if constexpr (KSPLIT) {
        Ag  += (size_t)kidx * Kext;
        Btg += (size_t)kidx * Kext;
        if (kidx) Cg = Cg2;
    }
    const int NT = Kext >> 6;

    f32x4 acc[8][4];
    #pragma unroll
    for (int i = 0; i < 8; i++)
        #pragma unroll
        for (int j = 0; j < 4; j++) acc[i][j] = (f32x4){0.f,0.f,0.f,0.f};

    stage_half(&Ag [(size_t)(m0      ) * ldk      ], ldk, &smA[0][0][0], w, lane);
    stage_half(&Ag [(size_t)(m0 + 128) * ldk      ], ldk, &smA[0][1][0], w, lane);
    stage_half(&Btg[(size_t)(n0      ) * ldk      ], ldk, &smB[0][0][0], w, lane);
    stage_half(&Btg[(size_t)(n0 + 128) * ldk      ], ldk, &smB[0][1][0], w, lane);
    stage_half(&Ag [(size_t)(m0      ) * ldk + 64 ], ldk, &smA[1][0][0], w, lane);
    stage_half(&Btg[(size_t)(n0      ) * ldk + 64 ], ldk, &smB[1][0][0], w, lane);
    stage_half(&Btg[(size_t)(n0 + 128) * ldk + 64 ], ldk, &smB[1][1][0], w, lane);
    VMCNT(6);
    __builtin_amdgcn_s_barrier();

    for (int t = 0; t < NT; ++t) {
        const int d = t & 1;
        const u16* As = &smA[d][wm][0];
        const u16* Bs = &smB[d][wn >> 1][0];
        const int rb = (wn & 1) * 64;

        bf16x8 aF[4][2], bLo[2][2], bHi[2][2];

        // ---- phase 1
        #pragma unroll
        for (int i = 0; i < 4; i++)
            #pragma unroll
            for (int ks = 0; ks < 2; ks++)
                aF[i][ks] = *(const bf16x8*)&As[(i*16 + lr)*64 + ((ks*32 + kh*8) ^ swz)];
        #pragma unroll
        for (int j = 0; j < 2; j++)
            #pragma unroll
            for (int ks = 0; ks < 2; ks++)
                bLo[j][ks] = *(const bf16x8*)&Bs[(rb + j*16 + lr)*64 + ((ks*32 + kh*8) ^ swz)];
        if (t + 1 < NT)
            stage_half(&Ag[(size_t)(m0 + 128) * ldk + (t+1)*64], ldk, &smA[d^1][1][0], w, lane);
        __builtin_amdgcn_s_barrier();
        __builtin_amdgcn_s_setprio(1);
        #pragma unroll
        for (int i = 0; i < 4; i++)
            #pragma unroll
            for (int j = 0; j < 2; j++)
                #pragma unroll
                for (int ks = 0; ks < 2; ks++)
                    acc[i][j] = __builtin_amdgcn_mfma_f32_16x16x32_bf16(aF[i][ks], bLo[j][ks], acc[i][j], 0, 0, 0);
        __builtin_amdgcn_s_setprio(0);
        __builtin_amdgcn_s_barrier();

        // ---- phase 2
        #pragma unroll
        for (int j = 0; j < 2; j++)
            #pragma unroll
            for (int ks = 0; ks < 2; ks++)
                bHi[j][ks] = *(const bf16x8*)&Bs[(rb + (2+j)*16 + lr)*64 + ((ks*32 + kh*8) ^ swz)];
        __builtin_amdgcn_s_barrier();
        __builtin_amdgcn_s_setprio(1);
        #pragma unroll
        for (int i = 0; i < 4; i++)
            #pragma unroll
            for (int j = 0; j < 2; j++)
                #pragma unroll
                for (int ks = 0; ks < 2; ks++)
                    acc[i][2+j] = __builtin_amdgcn_mfma_f32_16x16x32_bf16(aF[i][ks], bHi[j][ks], acc[i][2+j], 0, 0, 0);
        __builtin_amdgcn_s_setprio(0);
        __builtin_amdgcn_s_barrier();

        // ---- phase 3
        #pragma unroll
        for (int i = 0; i < 4; i++)
            #pragma unroll
            for (int ks = 0; ks < 2; ks++)
                aF[i][ks] = *(const bf16x8*)&As[(64 + i*16 + lr)*64 + ((ks*32 + kh*8) ^ swz)];
        if (t + 2 < NT)
            stage_half(&Btg[(size_t)(n0) * ldk + (t+2)*64], ldk, &smB[d][0][0], w, lane);
        __builtin_amdgcn_s_barrier();
        __builtin_amdgcn_s_setprio(1);
        #pragma unroll
        for (int i = 0; i < 4; i++)
            #pragma unroll
            for (int j = 0; j < 2; j++)
                #pragma unroll
                for (int ks = 0; ks < 2; ks++)
                    acc[4+i][j] = __builtin_amdgcn_mfma_f32_16x16x32_bf16(aF[i][ks], bLo[j][ks], acc[4+i][j], 0, 0, 0);
        __builtin_amdgcn_s_setprio(0);
        __builtin_amdgcn_s_barrier();

        // ---- phase 4
        if (t + 2 < NT) {
            stage_half(&Btg[(size_t)(n0 + 128) * ldk + (t+2)*64], ldk, &smB[d][1][0], w, lane);
            stage_half(&Ag [(size_t)(m0      ) * ldk + (t+2)*64], ldk, &smA[d][0][0], w, lane);
        }
        __builtin_amdgcn_s_barrier();
        __builtin_amdgcn_s_setprio(1);
        #pragma unroll
        for (int i = 0; i < 4; i++)
            #pragma unroll
            for (int j = 0; j < 2; j++)
                #pragma unroll
                for (int ks = 0; ks < 2; ks++)
                    acc[4+i][2+j] = __builtin_amdgcn_mfma_f32_16x16x32_bf16(aF[i][ks], bHi[j][ks], acc[4+i][2+j], 0, 0, 0);
        __builtin_amdgcn_s_setprio(0);
        if (t < NT - 2)       { VMCNT(6); }
        else if (t == NT - 2) { VMCNT(0); }
        __builtin_amdgcn_s_barrier();
    }

    #pragma unroll
    for (int mf = 0; mf < 8; mf++) {
        #pragma unroll
        for (int nf = 0; nf < 4; nf++) {
            int r = m0 + wm*128 + mf*16 + kh*4;
            int cidx = n0 + wn*64 + nf*16 + lr;
            #pragma unroll
            for (int q = 0; q < 4; q++) {
                if constexpr (sizeof(TC) == 4) Cg[(size_t)(r+q)*ldc + cidx] = acc[mf][nf][q];
                else                           Cg[(size_t)(r+q)*ldc + cidx] = f2us(acc[mf][nf][q]);
            }
        }
    }
}

// ---------- GEMM1 tail: N=512, K-split-4, 2-phase 128x128, f32 partials ----------
// grid = 512 blocks: tile = bid>>2 (32 m x 4 n), kidx = bid&3 (Kext=512 each).
__global__ __launch_bounds__(256)
void gemm_tail_ks4(const u16* __restrict__ A, const u16* __restrict__ Bt,
                   float* __restrict__ Cp, int M, int ldk)
{
    __shared__ u16 Asm[128][32];
    __shared__ u16 Bsm[128][32];
    const int t = threadIdx.x;
    const int lane = t & 63, w = t >> 6;
    const int wr = w >> 1, wc = w & 1;
    const int lr = lane & 15, kh = lane >> 4;

    const int bid = blockIdx.x;
    const int kidx = bid & 3, tile = bid >> 2;
    const int m0 = (tile >> 2) * 128;
    const int n0 = (tile & 3) * 128;

    const u16* Ak = A  + kidx * 512;
    const u16* Bk = Bt + kidx * 512;
    float* C = Cp + (size_t)kidx * M * 512;

    f32x4 acc[4][4];
    #pragma unroll
    for (int i = 0; i < 4; i++)
        #pragma unroll
        for (int j = 0; j < 4; j++) acc[i][j] = (f32x4){0.f,0.f,0.f,0.f};

    for (int k0 = 0; k0 < 512; k0 += 32) {
        #pragma unroll
        for (int i = 0; i < 2; i++) {
            int cb = i * 256 + w * 64;
            int chunk = cb + lane;
            int row = chunk >> 2, kb = chunk & 3;
            gload_lds16(&Ak[(size_t)(m0 + row) * ldk + k0 + kb * 8], &Asm[0][0] + cb * 8);
            gload_lds16(&Bk[(size_t)(n0 + row) * ldk + k0 + kb * 8], &Bsm[0][0] + cb * 8);
        }
        __syncthreads();
        bf16x8 af[4], bf[4];
        #pragma unroll
        for (int i = 0; i < 4; i++)
            af[i] = *(const bf16x8*)&Asm[wr*64 + i*16 + lr][kh*8];
        #pragma unroll
        for (int j = 0; j < 4; j++)
            bf[j] = *(const bf16x8*)&Bsm[wc*64 + j*16 + lr][kh*8];
        #pragma unroll
        for (int i = 0; i < 4; i++)
            #pragma unroll
            for (int j = 0; j < 4; j++)
                acc[i][j] = __builtin_amdgcn_mfma_f32_16x16x32_bf16(af[i], bf[j], acc[i][j], 0, 0, 0);
        __syncthreads();
    }
    #pragma unroll
    for (int i = 0; i < 4; i++) {
        #pragma unroll
        for (int j = 0; j < 4; j++) {
            int r = m0 + wr*64 + i*16 + kh*4;
            int cidx = n0 + wc*64 + j*16 + lr;
            #pragma unroll
            for (int q = 0; q < 4; q++)
                C[(size_t)(r+q)*512 + cidx] = acc[i][j][q];
        }
    }
}

// ---------------- conv1d (K=4) + bias + SiLU, 8 channels/thread ----------------
__global__ __launch_bounds__(256)
void conv_silu(const u16* __restrict__ zx, const float* __restrict__ cw,
               const float* __restrict__ cb, u16* __restrict__ xconv,
               u16* __restrict__ Bbuf, u16* __restrict__ Cbuf)
{
    int idx = blockIdx.x * 256 + threadIdx.x;
    int cg = idx % (CONV_DIM / 8);
    int r  = idx / (CONV_DIM / 8);
    int c0 = cg * 8;
    int l  = r & (SEQ - 1);

    float y[8];
    {
        float4 b0 = *(const float4*)&cb[c0];
        float4 b1 = *(const float4*)&cb[c0 + 4];
        y[0]=b0.x; y[1]=b0.y; y[2]=b0.z; y[3]=b0.w;
        y[4]=b1.x; y[5]=b1.y; y[6]=b1.z; y[7]=b1.w;
    }
    float cwf[8][4];
    #pragma unroll
    for (int e = 0; e < 8; e++) {
        float4 v = *(const float4*)&cw[(c0 + e) * 4];
        cwf[e][0]=v.x; cwf[e][1]=v.y; cwf[e][2]=v.z; cwf[e][3]=v.w;
    }
    #pragma unroll
    for (int k = 0; k < 4; k++) {
        if (l + k - 3 >= 0) {
            u16x8 v = *(const u16x8*)&zx[(size_t)(r + k - 3) * LD_ZX + D_INNER + c0];
            #pragma unroll
            for (int e = 0; e < 8; e++) y[e] += us2f(v[e]) * cwf[e][k];
        }
    }
    u16x8 o;
    #pragma unroll
    for (int e = 0; e < 8; e++) {
        float s = y[e] / (1.f + expf(-y[e]));
        o[e] = f2us(s);
    }
    if (c0 < D_INNER)                *(u16x8*)&xconv[(size_t)r * D_INNER + c0] = o;
    else if (c0 < D_INNER + D_STATE) *(u16x8*)&Bbuf[(size_t)r * D_STATE + (c0 - D_INNER)] = o;
    else                             *(u16x8*)&Cbuf[(size_t)r * D_STATE + (c0 - D_INNER - D_STATE)] = o;
}

// ---------------- dt softplus + per-chunk cumsum ----------------
__global__ __launch_bounds__(256)
void dt_acs(const u16* __restrict__ zx, const float* __restrict__ Aparam,
            const float* __restrict__ dt_bias, float* __restrict__ dtT,
            float* __restrict__ Acs)
{
    __shared__ float sb[CHUNK];
    int blk = blockIdx.x;
    int c = blk & 7, h = (blk >> 3) & 63, b = blk >> 9;
    int t = threadIdx.x;
    int lg = c * CHUNK + t;
    int row = b * SEQ + lg;
    float x = us2f(zx[(size_t)row * LD_ZX + DT_OFF + h]) + dt_bias[h];
    float dt = (x > 20.f) ? x : log1pf(expf(x));
    float v = dt * Aparam[h];
    sb[t] = v; __syncthreads();
    #pragma unroll
    for (int off = 1; off < 256; off <<= 1) {
        float add = (t >= off) ? sb[t - off] : 0.f;
        __syncthreads();
        v += add; sb[t] = v;
        __syncthreads();
    }
    int o = (b * NHEADS + h) * SEQ + lg;
    dtT[o] = dt;
    Acs[o] = v;
}

// ---------------- per-chunk states via MFMA, bf16 out, swapped operands ----------------
// states^T orientation in D: acc2[j][i] = mfma(B-frag, x-frag): lane holds 4 consecutive n
// at fixed p -> u16x4 stores to states[p][n]. wgt folded into x staging (16 convs/thread).
__global__ __launch_bounds__(256)
void chunk_states_mfma(const u16* __restrict__ xconv, const u16* __restrict__ Bbuf,
                       const float* __restrict__ dtT, const float* __restrict__ Acs,
                       u16* __restrict__ states)
{
    __shared__ u16 Btsh[128][72];   // B^T [n][l] (raw copy, transposed)
    __shared__ u16 xtsh[64][72];    // (w*x)^T [p][l]
    __shared__ float acs_sh[CHUNK];
    __shared__ float dt_sh[CHUNK];

    const int blk = blockIdx.x;
    const int h = blk & 63, c = (blk >> 6) & 7, b = blk >> 9;
    const int t = threadIdx.x;
    const int lane = t & 63, w = t >> 6;
    const int wr = w >> 1, wc = w & 1;
    const int lr = lane & 15, kh = lane >> 4;
    const int bh = b * NHEADS + h;
    const size_t rowbase = (size_t)(b * SEQ + c * CHUNK);

    acs_sh[t] = Acs[(size_t)bh * SEQ + c * CHUNK + t];
    dt_sh[t]  = dtT[(size_t)bh * SEQ + c * CHUNK + t];
    __syncthreads();
    const float acs_last = acs_sh[CHUNK - 1];

    f32x4 acc[4][2];   // [j = n-block][i = p-block]
    #pragma unroll
    for (int j = 0; j < 4; j++)
        #pragma unroll
        for (int i = 0; i < 2; i++) acc[j][i] = (f32x4){0.f,0.f,0.f,0.f};

    for (int lt = 0; lt < 4; lt++) {
        __syncthreads();
        const int s = t & 63;
        const int sg = lt * 64 + s;
        const float wgt = dt_sh[sg] * expf(acs_last - acs_sh[sg]);
        {   // B^T staging, raw u16 (no conversion): 32 n's at column s
            int ng = (t >> 6) * 32;
            const u16* src = &Bbuf[(rowbase + sg) * D_STATE + ng];
            #pragma unroll
            for (int q = 0; q < 4; q++) {
                u16x8 v = *(const u16x8*)&src[q * 8];
                #pragma unroll
                for (int e = 0; e < 8; e++)
                    Btsh[ng + q*8 + e][s] = v[e];
            }
        }
        {   // (w*x)^T staging: 16 p's at column s, wgt folded here
            int pg = (t >> 6) * 16;
            const u16* src = &xconv[(rowbase + sg) * D_INNER + h * HEAD_DIM + pg];
            u16x8 v0 = *(const u16x8*)&src[0];
            u16x8 v1 = *(const u16x8*)&src[8];
            #pragma unroll
            for (int e = 0; e < 8; e++) {
                xtsh[pg + e][s]     = f2us(us2f(v0[e]) * wgt);
                xtsh[pg + 8 + e][s] = f2us(us2f(v1[e]) * wgt);
            }
        }
        __syncthreads();
        #pragma unroll
        for (int kk = 0; kk < 2; kk++) {
            bf16x8 xf[2], bf[4];
            #pragma unroll
            for (int i = 0; i < 2; i++)
                xf[i] = *(const bf16x8*)&xtsh[wr*32 + i*16 + lr][kk*32 + kh*8];
            #pragma unroll
            for (int j = 0; j < 4; j++)
                bf[j] = *(const bf16x8*)&Btsh[wc*64 + j*16 + lr][kk*32 + kh*8];
            #pragma unroll
            for (int j = 0; j < 4; j++)
                #pragma unroll
                for (int i = 0; i < 2; i++)
                    acc[j][i] = __builtin_amdgcn_mfma_f32_16x16x32_bf16(bf[j], xf[i], acc[j][i], 0, 0, 0);
        }
    }
    // D rows = n (j*16 + kh*4 + q), cols = p (i*16 + lr) -> u16x4 contiguous in n
    size_t base = ((size_t)((b*NCHUNK + c)*NHEADS + h)) * (HEAD_DIM * D_STATE);
    #pragma unroll
    for (int j = 0; j < 4; j++) {
        #pragma unroll
        for (int i = 0; i < 2; i++) {
            int p = wr*32 + i*16 + lr;
            int n = wc*64 + j*16 + kh*4;
            u16x4 o;
            #pragma unroll
            for (int q = 0; q < 4; q++) o[q] = f2us(acc[j][i][q]);
            *(u16x4*)&states[base + (size_t)p * D_STATE + n] = o;
        }
    }
}

// ---------------- inter-chunk recurrence, bf16 states, u16x8 vectorized ----------------
__global__ __launch_bounds__(256)
void state_recurrence(u16* __restrict__ states, const float* __restrict__ Acs)
{
    int idx = blockIdx.x * 256 + threadIdx.x;   // < BATCH*NHEADS*64*16 = 131072
    int n8 = idx & 15;
    int p  = (idx >> 4) & 63;
    int bh = idx >> 10;
    int b = bh >> 6, h = bh & 63;
    float E[8];
    #pragma unroll
    for (int e = 0; e < 8; e++) E[e] = 0.f;
    for (int c = 0; c < NCHUNK; c++) {
        size_t off = ((size_t)((b*NCHUNK + c)*NHEADS + h)) * 8192 + (size_t)p * 128 + n8 * 8;
        u16x8 sv = *(const u16x8*)&states[off];
        u16x8 ev;
        #pragma unroll
        for (int e = 0; e < 8; e++) ev[e] = f2us(E[e]);
        *(u16x8*)&states[off] = ev;
        float g = expf(Acs[(size_t)(b*NHEADS + h) * SEQ + c*CHUNK + 255]);
        #pragma unroll
        for (int e = 0; e < 8; e++) E[e] = g * E[e] + us2f(sv[e]);
    }
}

// ---------------- chunk output, MFMA, swapped-operand (prev now bf16) ----------------
__global__ __launch_bounds__(256, 1)
void chunk_output_mfma(const u16* __restrict__ xconv, const u16* __restrict__ Bbuf,
                       const u16* __restrict__ Cbuf, const float* __restrict__ dtT,
                       const float* __restrict__ Acs, const u16* __restrict__ states,
                       const float* __restrict__ Dparam, u16* __restrict__ Y)
{
    __shared__ u16 Bsm[64][130];       // B tile [s][n]; later prev [p][n]
    __shared__ u16 xt[64][72];         // x^T tile [p][s]
    __shared__ u16 Pt[4][64][72];      // per-wave P [l][s]
    __shared__ float acs_sh[CHUNK];
    __shared__ float dt_sh[CHUNK];

    const int blk = blockIdx.x;
    const int h = blk & 63, c = (blk >> 6) & 7, b = blk >> 9;
    const int t = threadIdx.x;
    const int lane = t & 63, w = t >> 6;
    const int lr = lane & 15, kh = lane >> 4;
    const int bh = b * NHEADS + h;
    const size_t rowbase = (size_t)(b * SEQ + c * CHUNK);

    acs_sh[t] = Acs[(size_t)bh * SEQ + c * CHUNK + t];
    dt_sh[t]  = dtT[(size_t)bh * SEQ + c * CHUNK + t];

    bf16x8 af[4][4];
    #pragma unroll
    for (int i = 0; i < 4; i++)
        #pragma unroll
        for (int kk = 0; kk < 4; kk++)
            af[i][kk] = *(const bf16x8*)&Cbuf[(rowbase + w*64 + i*16 + lr) * D_STATE + kk*32 + kh*8];

    __syncthreads();
    float acs_l[4];
    #pragma unroll
    for (int i = 0; i < 4; i++) acs_l[i] = acs_sh[w*64 + i*16 + lr];

    f32x4 yacc[4][4];                   // [j=p-block][i=l-block]
    #pragma unroll
    for (int j = 0; j < 4; j++)
        #pragma unroll
        for (int i = 0; i < 4; i++) yacc[j][i] = (f32x4){0.f,0.f,0.f,0.f};

    for (int st = 0; st < 4; st++) {
        __syncthreads();
        {
            int sr = t >> 2, cg = (t & 3) * 32;
            const u16* src = &Bbuf[(rowbase + st*64 + sr) * D_STATE + cg];
            #pragma unroll
            for (int q = 0; q < 4; q++)
                *(u16x8*)&Bsm[sr][cg + q*8] = *(const u16x8*)&src[q*8];
        }
        {
            int s = t & 63, pg = t >> 6;
            const u16* src = &xconv[(rowbase + st*64 + s) * D_INNER + h*HEAD_DIM + pg*16];
            u16x8 v0 = *(const u16x8*)&src[0];
            u16x8 v1 = *(const u16x8*)&src[8];
            #pragma unroll
            for (int q = 0; q < 8; q++) { xt[pg*16 + q][s] = v0[q]; xt[pg*16 + 8 + q][s] = v1[q]; }
        }
        __syncthreads();
        if (st > w) continue;

        f32x4 sacc[4][4];
        #pragma unroll
        for (int js = 0; js < 4; js++)
            #pragma unroll
            for (int i = 0; i < 4; i++) sacc[js][i] = (f32x4){0.f,0.f,0.f,0.f};
        #pragma unroll
        for (int kk = 0; kk < 4; kk++) {
            bf16x8 bA[4];
            #pragma unroll
            for (int js = 0; js < 4; js++)
                bA[js] = *(const bf16x8*)&Bsm[js*16 + lr][kk*32 + kh*8];
            #pragma unroll
            for (int js = 0; js < 4; js++)
                #pragma unroll
                for (int i = 0; i < 4; i++)
                    sacc[js][i] = __builtin_amdgcn_mfma_f32_16x16x32_bf16(bA[js], af[i][kk], sacc[js][i], 0, 0, 0);
        }
        #pragma unroll
        for (int js = 0; js < 4; js++) {
            int sg0 = st*64 + js*16 + kh*4;
            float as[4], ds[4];
            #pragma unroll
            for (int q = 0; q < 4; q++) { as[q] = acs_sh[sg0 + q]; ds[q] = dt_sh[sg0 + q]; }
            #pragma unroll
            for (int i = 0; i < 4; i++) {
                int lg = w*64 + i*16 + lr;
                u16x4 pv;
                #pragma unroll
                for (int q = 0; q < 4; q++) {
                    float fac = (sg0 + q <= lg) ? expf(fminf(acs_l[i] - as[q], 0.f)) * ds[q] : 0.f;
                    pv[q] = f2us(sacc[js][i][q] * fac);
                }
                *(u16x4*)&Pt[w][i*16 + lr][js*16 + kh*4] = pv;
            }
        }
        #pragma unroll
        for (int kk2 = 0; kk2 < 2; kk2++) {
            bf16x8 xA[4], pB[4];
            #pragma unroll
            for (int j = 0; j < 4; j++)
                xA[j] = *(const bf16x8*)&xt[j*16 + lr][kk2*32 + kh*8];
            #pragma unroll
            for (int i = 0; i < 4; i++)
                pB[i] = *(const bf16x8*)&Pt[w][i*16 + lr][kk2*32 + kh*8];
            #pragma unroll
            for (int j = 0; j < 4; j++)
                #pragma unroll
                for (int i = 0; i < 4; i++)
                    yacc[j][i] = __builtin_amdgcn_mfma_f32_16x16x32_bf16(xA[j], pB[i], yacc[j][i], 0, 0, 0);
        }
    }

    // Y_off: prev now bf16 -> straight u16x8 copies into Bsm [p][n]
    __syncthreads();
    {
        int p = t >> 2, ng = (t & 3) * 32;
        const u16* src = &states[((size_t)((b*NCHUNK + c)*NHEADS + h)) * 8192 + (size_t)p * 128 + ng];
        #pragma unroll
        for (int q = 0; q < 4; q++)
            *(u16x8*)&Bsm[p][ng + q*8] = *(const u16x8*)&src[q*8];
    }
    __syncthreads();
    {
        float el[4];
        #pragma unroll
        for (int i = 0; i < 4; i++) el[i] = expf(acs_l[i]);
        #pragma unroll
        for (int kk = 0; kk < 4; kk++) {
            bf16x8 pvA[4];
            #pragma unroll
            for (int j = 0; j < 4; j++)
                pvA[j] = *(const bf16x8*)&Bsm[j*16 + lr][kk*32 + kh*8];
            #pragma unroll
            for (int i = 0; i < 4; i++) {
                bf16x8 ae;
                #pragma unroll
                for (int e = 0; e < 8; e++)
                    ae[e] = (short)f2us(us2f((u16)af[i][kk][e]) * el[i]);
                #pragma unroll
                for (int j = 0; j < 4; j++)
                    yacc[j][i] = __builtin_amdgcn_mfma_f32_16x16x32_bf16(pvA[j], ae, yacc[j][i], 0, 0, 0);
            }
        }
    }

    float Dh = Dparam[h];
    #pragma unroll
    for (int i = 0; i < 4; i++) {
        #pragma unroll
        for (int j = 0; j < 4; j++) {
            size_t o = (rowbase + w*64 + i*16 + lr) * D_INNER + h*HEAD_DIM + j*16 + kh*4;
            u16x4 xv = *(const u16x4*)&xconv[o];
            u16x4 ov;
            #pragma unroll
            for (int q = 0; q < 4; q++)
                ov[q] = f2us(yacc[j][i][q] + Dh * us2f(xv[q]));
            *(u16x4*)&Y[o] = ov;
        }
    }
}

// ---------------- gated RMSNorm ----------------
__global__ __launch_bounds__(256)
void gated_rmsnorm_k(u16* __restrict__ Y, const u16* __restrict__ zx,
                     const float* __restrict__ nw)
{
    __shared__ float xs[D_INNER];
    __shared__ float red[8];
    int row = blockIdx.x;
    int t = threadIdx.x;
    float ss = 0.f;
    for (int i = t*8; i < D_INNER; i += 2048) {
        u16x8 yv = *(const u16x8*)&Y[(size_t)row * D_INNER + i];
        u16x8 zv = *(const u16x8*)&zx[(size_t)row * LD_ZX + i];
        #pragma unroll
        for (int q = 0; q < 8; q++) {
            float x = us2f(yv[q]) * siluf(us2f(zv[q]));
            xs[i + q] = x;
            ss += x * x;
        }
    }
    #pragma unroll
    for (int off = 32; off > 0; off >>= 1) ss += __shfl_down(ss, off);
    int wid = t >> 6, lane = t & 63;
    if (lane == 0) red[wid] = ss;
    __syncthreads();
    if (t == 0) {
        float tot = red[0] + red[1] + red[2] + red[3];
        red[0] = rsqrtf(tot / (float)D_INNER + EPS_RMS);
    }
    __syncthreads();
    float sc = red[0];
    for (int i = t*8; i < D_INNER; i += 2048) {
        u16x8 o;
        #pragma unroll
        for (int q = 0; q < 8; q++) o[q] = f2us(xs[i + q] * sc * nw[i + q]);
        *(u16x8*)&Y[(size_t)row * D_INNER + i] = o;
    }
}

__global__ void ws_fail_k(float* out, float mb){ out[threadIdx.x] = mb; }

// ---------------- launch ----------------
extern "C" void kernel_launch(void* const* d_in, const int* in_sizes, int n_in,
                              void* d_out, int out_size, void* d_ws, size_t ws_size,
                              hipStream_t stream)
{
    const float* hidden  = (const float*)d_in[0];
    const float* W_in    = (const float*)d_in[1];
    const float* conv_w  = (const float*)d_in[2];
    const float* conv_b  = (const float*)d_in[3];
    const float* Aparam  = (const float*)d_in[4];
    const float* Dparam  = (const float*)d_in[5];
    const float* dt_bias = (const float*)d_in[6];
    const float* norm_w  = (const float*)d_in[7];
    const float* W_out   = (const float*)d_in[8];
    float* out = (float*)d_out;

    const int M = BATCH * SEQ;  // 4096

    size_t off = 0;
    char* wsb = (char*)d_ws;
    u16*   zx     = (u16*)  (wsb + off); off += (size_t)M * LD_ZX * 2;
    u16*   xconv  = (u16*)  (wsb + off); off += (size_t)M * D_INNER * 2;
    u16*   Bbuf   = (u16*)  (wsb + off); off += (size_t)M * D_STATE * 2;
    u16*   Cbuf   = (u16*)  (wsb + off); off += (size_t)M * D_STATE * 2;
    float* dtT    = (float*)(wsb + off); off += (size_t)BATCH * NHEADS * SEQ * 4;
    float* Acs    = (float*)(wsb + off); off += (size_t)BATCH * NHEADS * SEQ * 4;
    u16*   states = (u16*)  (wsb + off); off += (size_t)BATCH * NCHUNK * NHEADS * HEAD_DIM * D_STATE * 2; // bf16 now
    u16*   Ybuf   = (u16*)  (wsb + off); off += (size_t)M * D_INNER * 2;
    u16*   hbf    = (u16*)  (wsb + off); off += (size_t)M * D_MODEL * 2;
    u16*   WtIn   = (u16*)  (wsb + off); off += (size_t)LD_ZX * D_MODEL * 2;
    u16*   WtOut  = (u16*)  (wsb + off); off += (size_t)D_MODEL * D_INNER * 2;
    // tail partials (4 x M x 512 f32 = 33.5 MB) alias [states..Ybuf): consumed by add4_cvt
    // BEFORE chunk_states/chunk_output write states/Ybuf. GEMM2 partial aliases zx (dead
    // after gated_rmsnorm).
    float* tailp  = (float*)states;
    float* tmpf   = (float*)zx;

    if (off > ws_size) {
        ws_fail_k<<<1, 64, 0, stream>>>(out, (float)(ws_size >> 20));
        return;
    }

    cvt_bf16<<<(M * D_MODEL / 4 + 255) / 256, 256, 0, stream>>>(hidden, hbf, M * D_MODEL / 4);
    transpose_cvt<<<dim3(D_MODEL/64, LD_ZX/64), 256, 0, stream>>>(W_in, WtIn, D_MODEL, D_IN_PROJ);
    transpose_cvt<<<dim3(D_INNER/64, D_MODEL/64), 256, 0, stream>>>(W_out, WtOut, D_INNER, D_MODEL);

    // GEMM1 main: zx[:, 0:8192] — 512 blocks = exactly 2 CU-rounds
    gemm_8ph<u16, false><<<(8192/256) * (M/256), 512, 0, stream>>>(
        hbf, WtIn, zx, nullptr, M, 8192, D_MODEL, D_MODEL, LD_ZX);
    // GEMM1 tail: cols [8192:8704] — K-split-4, 512 blocks, f32 partials + fused add/cvt
    gemm_tail_ks4<<<512, 256, 0, stream>>>(hbf, WtIn + (size_t)8192 * D_MODEL, tailp, M, D_MODEL);
    add4_cvt_tail<<<(M * 512 / 8) / 256, 256, 0, stream>>>(tailp, zx, M);

    conv_silu<<<(M * CONV_DIM / 8) / 256, 256, 0, stream>>>(zx, conv_w, conv_b, xconv, Bbuf, Cbuf);
    dt_acs<<<BATCH * NHEADS * NCHUNK, 256, 0, stream>>>(zx, Aparam, dt_bias, dtT, Acs);
    chunk_states_mfma<<<BATCH * NCHUNK * NHEADS, 256, 0, stream>>>(xconv, Bbuf, dtT, Acs, states);
    state_recurrence<<<(BATCH * NHEADS * 64 * 16) / 256, 256, 0, stream>>>(states, Acs);
    chunk_output_mfma<<<BATCH * NCHUNK * NHEADS, 256, 0, stream>>>(xconv, Bbuf, Cbuf, dtT, Acs, states, Dparam, Ybuf);
    gated_rmsnorm_k<<<M, 256, 0, stream>>>(Ybuf, zx, norm_w);   // last reader of zx

    // GEMM2 K-split-2: 256 blocks = exactly 1 CU-round; then out += tmpf
    gemm_8ph<float, true><<<2 * (D_MODEL/256) * (M/256), 512, 0, stream>>>(
        Ybuf, WtOut, out, tmpf, M, D_MODEL, D_INNER/2, D_INNER, D_MODEL);
    add_f32<<<(M * D_MODEL / 4 + 255) / 256, 256, 0, stream>>>(out, tmpf, M * D_MODEL / 4);
}